// Round 24
// baseline (140.742 us; speedup 1.0000x reference)
//
#include <hip/hip_runtime.h>
#include <hip/hip_bf16.h>

#define B_   2
#define T_   2048
#define D_   1024
#define H_   16
#define HD_  64
#define M_TOT (B_*T_)    // 4096
#define N_QKV (3*D_)     // 3072

typedef __attribute__((ext_vector_type(8))) short bf16x8;
typedef __attribute__((ext_vector_type(4))) float f32x4;
typedef __attribute__((ext_vector_type(16))) float f32x16;

static __device__ __forceinline__ short f2bf(float f) {
    union { __hip_bfloat16 h; short s; } u;
    u.h = __float2bfloat16(f);
    return u.s;
}
static __device__ __forceinline__ unsigned pack2(float a, float b) {
    return (unsigned)(unsigned short)f2bf(a) | ((unsigned)(unsigned short)f2bf(b) << 16);
}
// HW packed f32->bf16 (RNE): D.lo16 = bf16(lo), D.hi16 = bf16(hi). 1 VALU op.
static __device__ __forceinline__ unsigned cvtpk(float lo, float hi) {
    unsigned r;
    asm("v_cvt_pk_bf16_f32 %0, %1, %2" : "=v"(r) : "v"(lo), "v"(hi));
    return r;
}
static __device__ __forceinline__ float exp2_fast(float x) {
    return __builtin_amdgcn_exp2f(x);
}
static __device__ __forceinline__ f32x16 zero16() {
    f32x16 z;
    #pragma unroll
    for (int i = 0; i < 16; ++i) z[i] = 0.f;
    return z;
}
// async global->LDS DMA, 16B per lane. LDS dest = wave-uniform base + lane*16.
static __device__ __forceinline__ void gload16(const void* g, void* l) {
    __builtin_amdgcn_global_load_lds(
        (__attribute__((address_space(1))) unsigned int*)(unsigned long long)g,
        (__attribute__((address_space(3))) unsigned int*)l, 16, 0, 0);
}
// NOTE (R9-R12): permlane32_swap failed factorial -> shfl_xor PV (verified).
// NOTE (R14): counted-vmcnt in attn neutral. NOTE (R16): T15 regressed.
// NOTE (R17): depth-2 GEMM prefetch neutral (kept). NOTE (R18/R19): split-K
// net negative. NOTE (R20): bh-major grid (kept, FETCH 69.7->12.3MB).
// NOTE (R21): cvt_pk P-pack -3us (kept). NOTE (R22): setprio regressed.
// NOTE (R23): KVBLK=128 window neutral. R24: 4 waves x 64 q-rows -- all
// waves previously read byte-identical K/V fragments (addr = f(lane) only);
// 4 waves serving 2 q-groups each HALVES per-CU DS reads (kf/vf shared by
// both groups' MFMAs); TLP(2/SIMD)->ILP(2 indep chains/wave).

// ---------------------------------------------------------------------------
// x fp32 -> bf16, straight copy (8 elems/thread)
__global__ __launch_bounds__(256) void convert_x(const float* __restrict__ x,
                                                 short* __restrict__ xb, int n8) {
    int i = blockIdx.x * blockDim.x + threadIdx.x;
    if (i >= n8) return;
    const float4* p = (const float4*)x + (size_t)i * 2;
    float4 a = p[0], b = p[1];
    bf16x8 o;
    o[0]=f2bf(a.x); o[1]=f2bf(a.y); o[2]=f2bf(a.z); o[3]=f2bf(a.w);
    o[4]=f2bf(b.x); o[5]=f2bf(b.y); o[6]=f2bf(b.z); o[7]=f2bf(b.w);
    *((bf16x8*)xb + i) = o;
}

// in [K][N] fp32  ->  out [N][K] bf16 (B^T layout for GEMM), 64x64 LDS tiles
__global__ __launch_bounds__(256) void transpose_convert(const float* __restrict__ in,
                                                         short* __restrict__ out,
                                                         int K, int N) {
    __shared__ short tile[64][65];
    int k0 = blockIdx.y * 64, n0 = blockIdx.x * 64;
    int t = threadIdx.x;
    #pragma unroll
    for (int i = 0; i < 16; ++i) {
        int idx = i * 256 + t;
        int r = idx >> 6, c = idx & 63;
        tile[r][c] = f2bf(in[(size_t)(k0 + r) * N + n0 + c]);
    }
    __syncthreads();
    #pragma unroll
    for (int i = 0; i < 16; ++i) {
        int idx = i * 256 + t;
        int r = idx >> 6, c = idx & 63;     // r: n-local, c: k-local
        out[(size_t)(n0 + r) * K + k0 + c] = tile[c][r];
    }
}

// ---------------------------------------------------------------------------
// BK=32 GEMM with depth-2 prefetch (R17-verified). C = A*BT^T + bias.
#define QSC 0.18033688f   // 0.125 * log2(e)
template<int BM, int BN, int MODE>
__global__ __launch_bounds__(256)
void gemm_dl(const short* __restrict__ A, const short* __restrict__ BT,
             const float* __restrict__ bias, int M, int N, int K,
             short* __restrict__ qo, short* __restrict__ ko,
             short* __restrict__ vo, float* __restrict__ fo) {
    constexpr int BUF = (BM + BN) * 64;        // bytes per stage buffer (64B rows)
    constexpr int NL = (BM + BN) / 64;         // DMA instrs per thread per stage
    __shared__ char smem[3 * BUF];
    const int t = threadIdx.x, w = t >> 6, l = t & 63;
    const int qi_l = l & 15, hi_l = l >> 4;
    const int m0 = blockIdx.y * BM, n0 = blockIdx.x * BN;
    const int wr = w >> 1, wc = w & 1;
    constexpr int MI = BM / 32, NI = BN / 32;

    f32x4 acc[MI][NI];
    #pragma unroll
    for (int mi = 0; mi < MI; ++mi)
        #pragma unroll
        for (int ni = 0; ni < NI; ++ni)
            acc[mi][ni] = (f32x4){0.f, 0.f, 0.f, 0.f};

    const int lrow = l >> 2;                     // 0..15 rows within one 1KB DMA
    const int lch  = ((l & 3) ^ (lrow & 3)) * 8; // pre-swizzled source chunk (elems)

    auto stage = [&](char* dst, int k0) {
        #pragma unroll
        for (int i = 0; i < BM / 64; ++i) {
            int rb = w * (BM / 4) + i * 16;
            gload16(A + (size_t)(m0 + rb + lrow) * K + k0 + lch, dst + rb * 64);
        }
        #pragma unroll
        for (int i = 0; i < BN / 64; ++i) {
            int rb = w * (BN / 4) + i * 16;
            gload16(BT + (size_t)(n0 + rb + lrow) * K + k0 + lch, dst + BM * 64 + rb * 64);
        }
    };

    const int nt = K / 32;
    stage(smem, 0);
    if (nt > 1) stage(smem + BUF, 32);
    for (int it = 0; it < nt; ++it) {
        if (it + 2 < nt) {
            stage(smem + ((it + 2) % 3) * BUF, (it + 2) * 32);  // t+2 in flight
            if constexpr (NL == 4)      asm volatile("s_waitcnt vmcnt(8)" ::: "memory");
            else if constexpr (NL == 3) asm volatile("s_waitcnt vmcnt(6)" ::: "memory");
            else                        asm volatile("s_waitcnt vmcnt(0)" ::: "memory");
        } else if (it + 1 < nt) {
            if constexpr (NL == 4)      asm volatile("s_waitcnt vmcnt(4)" ::: "memory");
            else if constexpr (NL == 3) asm volatile("s_waitcnt vmcnt(3)" ::: "memory");
            else                        asm volatile("s_waitcnt vmcnt(0)" ::: "memory");
        } else {
            asm volatile("s_waitcnt vmcnt(0)" ::: "memory");
        }
        __builtin_amdgcn_s_barrier();    // B1: tile t visible to all waves

        char* sA = smem + (it % 3) * BUF;
        char* sB = sA + BM * 64;
        bf16x8 af[MI], bfr[NI];
        #pragma unroll
        for (int mi = 0; mi < MI; ++mi) {
            int row = wr * (BM / 2) + mi * 16 + qi_l;
            int ad = row * 64 + ((hi_l ^ (row & 3)) * 16);
            af[mi] = *(const bf16x8*)(sA + ad);
        }
        #pragma unroll
        for (int ni = 0; ni < NI; ++ni) {
            int row = wc * (BN / 2) + ni * 16 + qi_l;
            int ad = row * 64 + ((hi_l ^ (row & 3)) * 16);
            bfr[ni] = *(const bf16x8*)(sB + ad);
        }
        #pragma unroll
        for (int mi = 0; mi < MI; ++mi)
            #pragma unroll
            for (int ni = 0; ni < NI; ++ni)
                acc[mi][ni] = __builtin_amdgcn_mfma_f32_16x16x32_bf16(af[mi], bfr[ni], acc[mi][ni], 0, 0, 0);

        __builtin_amdgcn_s_barrier();    // B2: buf[it%3] reads done
    }

    #pragma unroll
    for (int mi = 0; mi < MI; ++mi) {
        int rbase = m0 + wr * (BM / 2) + mi * 16 + 4 * hi_l;
        #pragma unroll
        for (int ni = 0; ni < NI; ++ni) {
            int n = n0 + wc * (BN / 2) + ni * 16 + qi_l;
            float bv = bias[n];
            #pragma unroll
            for (int r = 0; r < 4; ++r) {
                int mm = rbase + r;
                float c = acc[mi][ni][r] + bv;
                if (MODE == 0) {
                    int which = n >> 10, rest = n & 1023;
                    int h = rest >> 6, d = rest & 63;
                    int b = mm >> 11, tq = mm & 2047;
                    size_t bh = (size_t)(b * H_ + h);
                    if (which == 0)      qo[(bh * T_ + tq) * HD_ + d] = f2bf(c * QSC);
                    else if (which == 1) ko[(bh * T_ + tq) * HD_ + d] = f2bf(c);
                    else                 vo[(bh * HD_ + d) * T_ + tq] = f2bf(c);
                } else {
                    fo[(size_t)mm * N + n] = c;
                }
            }
        }
    }
}

// ---------------------------------------------------------------------------
// Flash attention R24: 4 waves x 64 q-rows (2 groups of 32 per wave),
// QBLK=256, KVBLK=64, swapped 32x32 MFMA, bh-major grid (XCD=bh%8).
// kf/vf LDS fragment reads are SHARED by both q-groups (addr = f(lane) only)
// -> per-CU DS reads halve vs the 8-wave version. Per-group online softmax,
// HW cvt_pk P-pack, shfl_xor PV redistribution (verified mapping).
// q,k: [B*H, T, Hd] bf16 (q pre-scaled by 1/8*log2e); vt: [B*H, Hd, T] bf16.
__global__ __launch_bounds__(256)
void attn(const short* __restrict__ q, const short* __restrict__ k,
          const short* __restrict__ vt, short* __restrict__ ao) {
    __shared__ char smem[32768];   // buf0: K@0 V@8192; buf1: K@16384 V@24576

    const int t = threadIdx.x, w = t >> 6, l = t & 63;
    const int q32 = l & 31, hi2 = l >> 5;
    const int swz = (l & 7) << 4;
    const int bh = blockIdx.x;                     // bh on x: XCD = bh % 8
    const int qbase = blockIdx.y * 256 + w * 64;   // this wave: 64 q-rows

    const short* qptrA = q + ((size_t)bh * T_ + qbase) * HD_;
    const short* qptrB = qptrA + 32 * HD_;
    const short* kbase = k + (size_t)bh * T_ * HD_;
    const short* vbase = vt + (size_t)bh * HD_ * T_;

    const int srow = w * 16 + (l >> 3);             // staging rows: srow, srow+8
    const int sch  = ((l & 7) ^ (l >> 3)) * 8;      // pre-swizzled source chunk

    // Q fragments for both groups
    bf16x8 qaA[4], qaB[4];
    #pragma unroll
    for (int kc = 0; kc < 4; ++kc) {
        qaA[kc] = *(const bf16x8*)(qptrA + q32 * HD_ + kc * 16 + hi2 * 8);
        qaB[kc] = *(const bf16x8*)(qptrB + q32 * HD_ + kc * 16 + hi2 * 8);
    }

    f32x16 oA0 = zero16(), oA1 = zero16(), oB0 = zero16(), oB1 = zero16();
    float mA = -1e30f, lA = 0.f, mB = -1e30f, lB = 0.f;

    auto stage = [&](int kb, char* dst) {
        gload16(kbase + (size_t)(kb + srow) * HD_ + sch,     dst + srow * 128);
        gload16(kbase + (size_t)(kb + srow + 8) * HD_ + sch, dst + (srow + 8) * 128);
        gload16(vbase + (size_t)srow * T_ + kb + sch,        dst + 8192 + srow * 128);
        gload16(vbase + (size_t)(srow + 8) * T_ + kb + sch,  dst + 8192 + (srow + 8) * 128);
    };

    stage(0, smem);
    __syncthreads();

    int cur = 0;
    for (int kb = 0; kb < T_; kb += 64) {
        char* sK = smem + cur * 16384;
        char* sV = sK + 8192;
        if (kb + 64 < T_) stage(kb + 64, smem + (cur ^ 1) * 16384);

        // QK^T for both groups; kf0/kf1 read ONCE, used by A and B
        f32x16 sA0 = zero16(), sA1 = zero16(), sB0 = zero16(), sB1 = zero16();
        #pragma unroll
        for (int kc = 0; kc < 4; ++kc) {
            int off = (kc * 32 + hi2 * 16) ^ swz;
            bf16x8 kf0 = *(const bf16x8*)(sK + q32 * 128 + off);
            bf16x8 kf1 = *(const bf16x8*)(sK + (32 + q32) * 128 + off);
            sA0 = __builtin_amdgcn_mfma_f32_32x32x16_bf16(kf0, qaA[kc], sA0, 0, 0, 0);
            sA1 = __builtin_amdgcn_mfma_f32_32x32x16_bf16(kf1, qaA[kc], sA1, 0, 0, 0);
            sB0 = __builtin_amdgcn_mfma_f32_32x32x16_bf16(kf0, qaB[kc], sB0, 0, 0, 0);
            sB1 = __builtin_amdgcn_mfma_f32_32x32x16_bf16(kf1, qaB[kc], sB1, 0, 0, 0);
        }

        // ---- softmax group A ----
        unsigned pkA0[8], pkA1[8];
        {
            float a8[8];
            #pragma unroll
            for (int i = 0; i < 8; ++i)
                a8[i] = fmaxf(fmaxf(sA0[i], sA0[i + 8]), fmaxf(sA1[i], sA1[i + 8]));
            float b0 = fmaxf(a8[0], a8[1]), b1 = fmaxf(a8[2], a8[3]);
            float b2 = fmaxf(a8[4], a8[5]), b3 = fmaxf(a8[6], a8[7]);
            float tm = fmaxf(fmaxf(b0, b1), fmaxf(b2, b3));
            tm = fmaxf(tm, __shfl_xor(tm, 32));
            if (!__all(tm <= mA + 8.f)) {
                float mnew = fmaxf(mA, tm);
                float fsc = exp2_fast(mA - mnew);
                lA *= fsc;
                #pragma unroll
                for (int i = 0; i < 16; ++i) { oA0[i] *= fsc; oA1[i] *= fsc; }
                mA = mnew;
            }
            #pragma unroll
            for (int i = 0; i < 16; ++i) {
                sA0[i] = exp2_fast(sA0[i] - mA);
                sA1[i] = exp2_fast(sA1[i] - mA);
            }
            float p8[8];
            #pragma unroll
            for (int i = 0; i < 8; ++i)
                p8[i] = (sA0[i] + sA0[i + 8]) + (sA1[i] + sA1[i + 8]);
            float ps = ((p8[0] + p8[1]) + (p8[2] + p8[3])) + ((p8[4] + p8[5]) + (p8[6] + p8[7]));
            ps += __shfl_xor(ps, 32);
            lA += ps;
            #pragma unroll
            for (int p = 0; p < 8; ++p) {
                pkA0[p] = cvtpk(sA0[2 * p], sA0[2 * p + 1]);
                pkA1[p] = cvtpk(sA1[2 * p], sA1[2 * p + 1]);
            }
        }
        // ---- softmax group B ----
        unsigned pkB0[8], pkB1[8];
        {
            float a8[8];
            #pragma unroll
            for (int i = 0; i < 8; ++i)
                a8[i] = fmaxf(fmaxf(sB0[i], sB0[i + 8]), fmaxf(sB1[i], sB1[i + 8]));
            float b0 = fmaxf(a8[0], a8[1]), b1 = fmaxf(a8[2], a8[3]);
            float b2 = fmaxf(a8[4], a8[5]), b3 = fmaxf(a8[6], a8[7]);
            float tm = fmaxf(fmaxf(b0, b1), fmaxf(b2, b3));
            tm = fmaxf(tm, __shfl_xor(tm, 32));
            if (!__all(tm <= mB + 8.f)) {
                float mnew = fmaxf(mB, tm);
                float fsc = exp2_fast(mB - mnew);
                lB *= fsc;
                #pragma unroll
                for (int i = 0; i < 16; ++i) { oB0[i] *= fsc; oB1[i] *= fsc; }
                mB = mnew;
            }
            #pragma unroll
            for (int i = 0; i < 16; ++i) {
                sB0[i] = exp2_fast(sB0[i] - mB);
                sB1[i] = exp2_fast(sB1[i] - mB);
            }
            float p8[8];
            #pragma unroll
            for (int i = 0; i < 8; ++i)
                p8[i] = (sB0[i] + sB0[i + 8]) + (sB1[i] + sB1[i + 8]);
            float ps = ((p8[0] + p8[1]) + (p8[2] + p8[3])) + ((p8[4] + p8[5]) + (p8[6] + p8[7]));
            ps += __shfl_xor(ps, 32);
            lB += ps;
            #pragma unroll
            for (int p = 0; p < 8; ++p) {
                pkB0[p] = cvtpk(sB0[2 * p], sB0[2 * p + 1]);
                pkB1[p] = cvtpk(sB1[2 * p], sB1[2 * p + 1]);
            }
        }

        // PV: vf0/vf1 read ONCE per chunk, used by both groups' fragments
        #pragma unroll
        for (int c = 0; c < 4; ++c) {
            int off = (c * 32 + hi2 * 16) ^ swz;
            bf16x8 vf0 = *(const bf16x8*)(sV + q32 * 128 + off);
            bf16x8 vf1 = *(const bf16x8*)(sV + (32 + q32) * 128 + off);

            // group A fragment
            {
                unsigned w0 = (c & 2) ? pkA1[(c & 1) * 4 + 0] : pkA0[(c & 1) * 4 + 0];
                unsigned w1 = (c & 2) ? pkA1[(c & 1) * 4 + 1] : pkA0[(c & 1) * 4 + 1];
                unsigned w2 = (c & 2) ? pkA1[(c & 1) * 4 + 2] : pkA0[(c & 1) * 4 + 2];
                unsigned w3 = (c & 2) ? pkA1[(c & 1) * 4 + 3] : pkA0[(c & 1) * 4 + 3];
                unsigned t0 = hi2 ? w0 : w2;
                unsigned t1 = hi2 ? w1 : w3;
                unsigned r0 = __shfl_xor(t0, 32);
                unsigned r1 = __shfl_xor(t1, 32);
                union { unsigned u[4]; bf16x8 v; } uf;
                uf.u[0] = hi2 ? r0 : w0;
                uf.u[1] = hi2 ? r1 : w1;
                uf.u[2] = hi2 ? w2 : r0;
                uf.u[3] = hi2 ? w3 : r1;
                oA0 = __builtin_amdgcn_mfma_f32_32x32x16_bf16(vf0, uf.v, oA0, 0, 0, 0);
                oA1 = __builtin_amdgcn_mfma_f32_32x32x16_bf16(vf1, uf.v, oA1, 0, 0, 0);
            }
            // group B fragment
            {
                unsigned w0 = (c & 2) ? pkB1[(c & 1) * 4 + 0] : pkB0[(c & 1) * 4 + 0];
                unsigned w1 = (c & 2) ? pkB1[(c & 1) * 4 + 1] : pkB0[(c & 1) * 4 + 1];
                unsigned w2 = (c & 2) ? pkB1[(c & 1) * 4 + 2] : pkB0[(c & 1) * 4 + 2];
                unsigned w3 = (c & 2) ? pkB1[(c & 1) * 4 + 3] : pkB0[(c & 1) * 4 + 3];
                unsigned t0 = hi2 ? w0 : w2;
                unsigned t1 = hi2 ? w1 : w3;
                unsigned r0 = __shfl_xor(t0, 32);
                unsigned r1 = __shfl_xor(t1, 32);
                union { unsigned u[4]; bf16x8 v; } uf;
                uf.u[0] = hi2 ? r0 : w0;
                uf.u[1] = hi2 ? r1 : w1;
                uf.u[2] = hi2 ? w2 : r0;
                uf.u[3] = hi2 ? w3 : r1;
                oB0 = __builtin_amdgcn_mfma_f32_32x32x16_bf16(vf0, uf.v, oB0, 0, 0, 0);
                oB1 = __builtin_amdgcn_mfma_f32_32x32x16_bf16(vf1, uf.v, oB1, 0, 0, 0);
            }
        }

        __syncthreads();    // DMA drained + all waves done with buf[cur]
        cur ^= 1;
    }

    const int b = bh >> 4, h = bh & 15;
    {
        const float inv = 1.f / lA;
        const int tq = qbase + q32;
        unsigned* aou = (unsigned*)(ao + ((size_t)(b * T_ + tq)) * D_ + h * HD_);
        #pragma unroll
        for (int pr = 0; pr < 8; ++pr) {
            int d0 = 2 * (pr & 1) + 8 * (pr >> 1) + 4 * hi2;
            aou[d0 >> 1]        = cvtpk(oA0[2 * pr] * inv, oA0[2 * pr + 1] * inv);
            aou[(32 + d0) >> 1] = cvtpk(oA1[2 * pr] * inv, oA1[2 * pr + 1] * inv);
        }
    }
    {
        const float inv = 1.f / lB;
        const int tq = qbase + 32 + q32;
        unsigned* aou = (unsigned*)(ao + ((size_t)(b * T_ + tq)) * D_ + h * HD_);
        #pragma unroll
        for (int pr = 0; pr < 8; ++pr) {
            int d0 = 2 * (pr & 1) + 8 * (pr >> 1) + 4 * hi2;
            aou[d0 >> 1]        = cvtpk(oB0[2 * pr] * inv, oB0[2 * pr + 1] * inv);
            aou[(32 + d0) >> 1] = cvtpk(oB1[2 * pr] * inv, oB1[2 * pr + 1] * inv);
        }
    }
}

// ---------------------------------------------------------------------------
extern "C" void kernel_launch(void* const* d_in, const int* in_sizes, int n_in,
                              void* d_out, int out_size, void* d_ws, size_t ws_size,
                              hipStream_t stream) {
    const float* x    = (const float*)d_in[0];
    const float* Wqkv = (const float*)d_in[1];
    const float* bqkv = (const float*)d_in[2];
    const float* Wout = (const float*)d_in[3];
    const float* bout = (const float*)d_in[4];
    float* out = (float*)d_out;

    char* ws = (char*)d_ws;
    short* xb  = (short*)(ws);                      // 8 MB  x bf16 [4096][1024]
    short* WqT = (short*)(ws + ((size_t)8  << 20)); // 6 MB  Wqkv^T bf16 [3072][1024]
    short* WoT = (short*)(ws + ((size_t)14 << 20)); // 2 MB  Wout^T bf16 [1024][1024]
    short* qb  = (short*)(ws + ((size_t)16 << 20)); // 8 MB  q [B*H][T][Hd]
    short* kb  = (short*)(ws + ((size_t)24 << 20)); // 8 MB  k [B*H][T][Hd]
    short* vtb = (short*)(ws + ((size_t)32 << 20)); // 8 MB  v^T [B*H][Hd][T]
    short* aob = (short*)(ws + ((size_t)40 << 20)); // 8 MB  attn out bf16 [4096][1024]

    convert_x<<<(M_TOT * D_ / 8 + 255) / 256, 256, 0, stream>>>(x, xb, M_TOT * D_ / 8);
    transpose_convert<<<dim3(N_QKV / 64, D_ / 64), 256, 0, stream>>>(Wqkv, WqT, D_, N_QKV);
    transpose_convert<<<dim3(D_ / 64, D_ / 64), 256, 0, stream>>>(Wout, WoT, D_, D_);

    gemm_dl<128, 128, 0><<<dim3(N_QKV / 128, M_TOT / 128), 256, 0, stream>>>(
        xb, WqT, bqkv, M_TOT, N_QKV, D_, qb, kb, vtb, nullptr);

    attn<<<dim3(B_ * H_, T_ / 256), 256, 0, stream>>>(qb, kb, vtb, aob);

    gemm_dl<128, 64, 1><<<dim3(D_ / 64, M_TOT / 128), 256, 0, stream>>>(
        aob, WoT, bout, M_TOT, D_, D_, nullptr, nullptr, nullptr, out);
}

// Round 25
// 123.268 us; speedup vs baseline: 1.1418x; 1.1418x over previous
//
#include <hip/hip_runtime.h>
#include <hip/hip_bf16.h>

#define B_   2
#define T_   2048
#define D_   1024
#define H_   16
#define HD_  64
#define M_TOT (B_*T_)    // 4096
#define N_QKV (3*D_)     // 3072

typedef __attribute__((ext_vector_type(8))) short bf16x8;
typedef __attribute__((ext_vector_type(4))) float f32x4;
typedef __attribute__((ext_vector_type(16))) float f32x16;

static __device__ __forceinline__ short f2bf(float f) {
    union { __hip_bfloat16 h; short s; } u;
    u.h = __float2bfloat16(f);
    return u.s;
}
static __device__ __forceinline__ unsigned pack2(float a, float b) {
    return (unsigned)(unsigned short)f2bf(a) | ((unsigned)(unsigned short)f2bf(b) << 16);
}
// HW packed f32->bf16 (RNE): D.lo16 = bf16(lo), D.hi16 = bf16(hi). 1 VALU op.
static __device__ __forceinline__ unsigned cvtpk(float lo, float hi) {
    unsigned r;
    asm("v_cvt_pk_bf16_f32 %0, %1, %2" : "=v"(r) : "v"(lo), "v"(hi));
    return r;
}
static __device__ __forceinline__ float exp2_fast(float x) {
    return __builtin_amdgcn_exp2f(x);
}
static __device__ __forceinline__ f32x16 zero16() {
    f32x16 z;
    #pragma unroll
    for (int i = 0; i < 16; ++i) z[i] = 0.f;
    return z;
}
// async global->LDS DMA, 16B per lane. LDS dest = wave-uniform base + lane*16.
static __device__ __forceinline__ void gload16(const void* g, void* l) {
    __builtin_amdgcn_global_load_lds(
        (__attribute__((address_space(1))) unsigned int*)(unsigned long long)g,
        (__attribute__((address_space(3))) unsigned int*)l, 16, 0, 0);
}
// Session ledger: (R9-R12) permlane32_swap failed 2x2 factorial -> shfl_xor
// PV (verified). (R14) counted-vmcnt in attn neutral. (R16) T15 att[2]
// regressed (VGPR 2x). (R17) depth-2 GEMM prefetch neutral (kept). (R18/R19)
// KV split-K net negative. (R20) bh-major grid: FETCH 69.7->12.3MB (kept).
// (R21) cvt_pk P-pack -3us (kept). (R22) setprio regressed. (R23) KVBLK=128
// window neutral. (R24) 4-wave dedup regressed hard (1 wave/SIMD: occupancy
// 10%, serial chains exposed -- this structure needs exactly 2 waves/SIMD).
// R25 (final): best verified combo = R21 attn body + cvtpk epilogue +
// fused weight-transpose launch (one dispatch for Wqkv+Wout).

// ---------------------------------------------------------------------------
// x fp32 -> bf16, straight copy (8 elems/thread)
__global__ __launch_bounds__(256) void convert_x(const float* __restrict__ x,
                                                 short* __restrict__ xb, int n8) {
    int i = blockIdx.x * blockDim.x + threadIdx.x;
    if (i >= n8) return;
    const float4* p = (const float4*)x + (size_t)i * 2;
    float4 a = p[0], b = p[1];
    bf16x8 o;
    o[0]=f2bf(a.x); o[1]=f2bf(a.y); o[2]=f2bf(a.z); o[3]=f2bf(a.w);
    o[4]=f2bf(b.x); o[5]=f2bf(b.y); o[6]=f2bf(b.z); o[7]=f2bf(b.w);
    *((bf16x8*)xb + i) = o;
}

// Fused weight transpose+convert: z==0 -> Wqkv[1024][3072] -> WqT[3072][1024];
// z==1 -> Wout[1024][1024] -> WoT[1024][1024]. K=1024 both. 64x64 LDS tiles.
// z==1 blocks with bx>=16 early-return (block-uniform, before any barrier).
__global__ __launch_bounds__(256)
void transpose_convert2(const float* __restrict__ in0, short* __restrict__ out0,
                        const float* __restrict__ in1, short* __restrict__ out1) {
    const float* in; short* out; int N;
    if (blockIdx.z == 0) { in = in0; out = out0; N = N_QKV; }
    else {
        if (blockIdx.x >= 16) return;
        in = in1; out = out1; N = D_;
    }
    __shared__ short tile[64][65];
    int k0 = blockIdx.y * 64, n0 = blockIdx.x * 64;
    int t = threadIdx.x;
    #pragma unroll
    for (int i = 0; i < 16; ++i) {
        int idx = i * 256 + t;
        int r = idx >> 6, c = idx & 63;
        tile[r][c] = f2bf(in[(size_t)(k0 + r) * N + n0 + c]);
    }
    __syncthreads();
    #pragma unroll
    for (int i = 0; i < 16; ++i) {
        int idx = i * 256 + t;
        int r = idx >> 6, c = idx & 63;     // r: n-local, c: k-local
        out[(size_t)(n0 + r) * D_ + k0 + c] = tile[c][r];
    }
}

// ---------------------------------------------------------------------------
// BK=32 GEMM with depth-2 prefetch (R17-verified). C = A*BT^T + bias.
#define QSC 0.18033688f   // 0.125 * log2(e)
template<int BM, int BN, int MODE>
__global__ __launch_bounds__(256)
void gemm_dl(const short* __restrict__ A, const short* __restrict__ BT,
             const float* __restrict__ bias, int M, int N, int K,
             short* __restrict__ qo, short* __restrict__ ko,
             short* __restrict__ vo, float* __restrict__ fo) {
    constexpr int BUF = (BM + BN) * 64;        // bytes per stage buffer (64B rows)
    constexpr int NL = (BM + BN) / 64;         // DMA instrs per thread per stage
    __shared__ char smem[3 * BUF];
    const int t = threadIdx.x, w = t >> 6, l = t & 63;
    const int qi_l = l & 15, hi_l = l >> 4;
    const int m0 = blockIdx.y * BM, n0 = blockIdx.x * BN;
    const int wr = w >> 1, wc = w & 1;
    constexpr int MI = BM / 32, NI = BN / 32;

    f32x4 acc[MI][NI];
    #pragma unroll
    for (int mi = 0; mi < MI; ++mi)
        #pragma unroll
        for (int ni = 0; ni < NI; ++ni)
            acc[mi][ni] = (f32x4){0.f, 0.f, 0.f, 0.f};

    const int lrow = l >> 2;                     // 0..15 rows within one 1KB DMA
    const int lch  = ((l & 3) ^ (lrow & 3)) * 8; // pre-swizzled source chunk (elems)

    auto stage = [&](char* dst, int k0) {
        #pragma unroll
        for (int i = 0; i < BM / 64; ++i) {
            int rb = w * (BM / 4) + i * 16;
            gload16(A + (size_t)(m0 + rb + lrow) * K + k0 + lch, dst + rb * 64);
        }
        #pragma unroll
        for (int i = 0; i < BN / 64; ++i) {
            int rb = w * (BN / 4) + i * 16;
            gload16(BT + (size_t)(n0 + rb + lrow) * K + k0 + lch, dst + BM * 64 + rb * 64);
        }
    };

    const int nt = K / 32;
    stage(smem, 0);
    if (nt > 1) stage(smem + BUF, 32);
    for (int it = 0; it < nt; ++it) {
        if (it + 2 < nt) {
            stage(smem + ((it + 2) % 3) * BUF, (it + 2) * 32);  // t+2 in flight
            if constexpr (NL == 4)      asm volatile("s_waitcnt vmcnt(8)" ::: "memory");
            else if constexpr (NL == 3) asm volatile("s_waitcnt vmcnt(6)" ::: "memory");
            else                        asm volatile("s_waitcnt vmcnt(0)" ::: "memory");
        } else if (it + 1 < nt) {
            if constexpr (NL == 4)      asm volatile("s_waitcnt vmcnt(4)" ::: "memory");
            else if constexpr (NL == 3) asm volatile("s_waitcnt vmcnt(3)" ::: "memory");
            else                        asm volatile("s_waitcnt vmcnt(0)" ::: "memory");
        } else {
            asm volatile("s_waitcnt vmcnt(0)" ::: "memory");
        }
        __builtin_amdgcn_s_barrier();    // B1: tile t visible to all waves

        char* sA = smem + (it % 3) * BUF;
        char* sB = sA + BM * 64;
        bf16x8 af[MI], bfr[NI];
        #pragma unroll
        for (int mi = 0; mi < MI; ++mi) {
            int row = wr * (BM / 2) + mi * 16 + qi_l;
            int ad = row * 64 + ((hi_l ^ (row & 3)) * 16);
            af[mi] = *(const bf16x8*)(sA + ad);
        }
        #pragma unroll
        for (int ni = 0; ni < NI; ++ni) {
            int row = wc * (BN / 2) + ni * 16 + qi_l;
            int ad = row * 64 + ((hi_l ^ (row & 3)) * 16);
            bfr[ni] = *(const bf16x8*)(sB + ad);
        }
        #pragma unroll
        for (int mi = 0; mi < MI; ++mi)
            #pragma unroll
            for (int ni = 0; ni < NI; ++ni)
                acc[mi][ni] = __builtin_amdgcn_mfma_f32_16x16x32_bf16(af[mi], bfr[ni], acc[mi][ni], 0, 0, 0);

        __builtin_amdgcn_s_barrier();    // B2: buf[it%3] reads done
    }

    #pragma unroll
    for (int mi = 0; mi < MI; ++mi) {
        int rbase = m0 + wr * (BM / 2) + mi * 16 + 4 * hi_l;
        #pragma unroll
        for (int ni = 0; ni < NI; ++ni) {
            int n = n0 + wc * (BN / 2) + ni * 16 + qi_l;
            float bv = bias[n];
            #pragma unroll
            for (int r = 0; r < 4; ++r) {
                int mm = rbase + r;
                float c = acc[mi][ni][r] + bv;
                if (MODE == 0) {
                    int which = n >> 10, rest = n & 1023;
                    int h = rest >> 6, d = rest & 63;
                    int b = mm >> 11, tq = mm & 2047;
                    size_t bh = (size_t)(b * H_ + h);
                    if (which == 0)      qo[(bh * T_ + tq) * HD_ + d] = f2bf(c * QSC);
                    else if (which == 1) ko[(bh * T_ + tq) * HD_ + d] = f2bf(c);
                    else                 vo[(bh * HD_ + d) * T_ + tq] = f2bf(c);
                } else {
                    fo[(size_t)mm * N + n] = c;
                }
            }
        }
    }
}

// ---------------------------------------------------------------------------
// Flash attention (best verified: R21 body): bh-major grid (XCD=bh%8 L2
// locality), 8 waves x 32 q-rows (QBLK=256), KVBLK=64, swapped 32x32 MFMA,
// HW cvt_pk P-pack, shfl_xor PV redistribution, cvtpk epilogue.
// q,k: [B*H, T, Hd] bf16 (q pre-scaled by 1/8*log2e); vt: [B*H, Hd, T] bf16.
__global__ __launch_bounds__(512)
void attn(const short* __restrict__ q, const short* __restrict__ k,
          const short* __restrict__ vt, short* __restrict__ ao) {
    __shared__ char smem[32768];   // buf0: K@0 V@8192; buf1: K@16384 V@24576

    const int t = threadIdx.x, w = t >> 6, l = t & 63;
    const int q32 = l & 31, hi2 = l >> 5;
    const int swz = (l & 7) << 4;
    const int bh = blockIdx.x;                     // bh on x: XCD = bh % 8
    const int q0 = blockIdx.y * 256 + w * 32;      // q-tile on y

    const short* qptr = q + ((size_t)bh * T_ + q0) * HD_;
    const short* kbase = k + (size_t)bh * T_ * HD_;
    const short* vbase = vt + (size_t)bh * HD_ * T_;

    const int srow = w * 8 + (l >> 3);              // staging row (this wave: 8 rows)
    const int sch  = ((l & 7) ^ (l >> 3)) * 8;      // pre-swizzled source chunk

    // Q fragments: B-operand of 32x32x16: lane holds Q[q=q32][d = kc*16 + hi2*8 + j]
    bf16x8 qa[4];
    #pragma unroll
    for (int kc = 0; kc < 4; ++kc)
        qa[kc] = *(const bf16x8*)(qptr + q32 * HD_ + kc * 16 + hi2 * 8);

    f32x16 o0 = zero16(), o1 = zero16();
    float m = -1e30f, lsum = 0.f;

    // prologue: stage tile 0 into buf 0 (1 K + 1 V DMA per thread)
    gload16(kbase + (size_t)srow * HD_ + sch, smem + srow * 128);
    gload16(vbase + (size_t)srow * T_ + sch,  smem + 8192 + srow * 128);
    __syncthreads();

    int cur = 0;
    for (int kb = 0; kb < T_; kb += 64) {
        char* sK = smem + cur * 16384;
        char* sV = sK + 8192;
        if (kb + 64 < T_) {
            char* nK = smem + (cur ^ 1) * 16384;
            gload16(kbase + (size_t)(kb + 64 + srow) * HD_ + sch, nK + srow * 128);
            gload16(vbase + (size_t)srow * T_ + (kb + 64) + sch,  nK + 8192 + srow * 128);
        }

        // S^T: two 32x32 tiles (kvt=0,1), accumulate over Hd in 4 chunks of 16
        f32x16 s0 = zero16(), s1 = zero16();
        #pragma unroll
        for (int kc = 0; kc < 4; ++kc) {
            int off = (kc * 32 + hi2 * 16) ^ swz;
            bf16x8 kf0 = *(const bf16x8*)(sK + q32 * 128 + off);
            s0 = __builtin_amdgcn_mfma_f32_32x32x16_bf16(kf0, qa[kc], s0, 0, 0, 0);
            bf16x8 kf1 = *(const bf16x8*)(sK + (32 + q32) * 128 + off);
            s1 = __builtin_amdgcn_mfma_f32_32x32x16_bf16(kf1, qa[kc], s1, 0, 0, 0);
        }

        // row max: 32 in-lane (tree) + 1 exchange with lane^32
        float a8[8];
        #pragma unroll
        for (int i = 0; i < 8; ++i)
            a8[i] = fmaxf(fmaxf(s0[i], s0[i + 8]), fmaxf(s1[i], s1[i + 8]));
        float b4_0 = fmaxf(a8[0], a8[1]), b4_1 = fmaxf(a8[2], a8[3]);
        float b4_2 = fmaxf(a8[4], a8[5]), b4_3 = fmaxf(a8[6], a8[7]);
        float tm = fmaxf(fmaxf(b4_0, b4_1), fmaxf(b4_2, b4_3));
        tm = fmaxf(tm, __shfl_xor(tm, 32));

        // defer-max (T13): skip O-rescale when max growth <= 8 (log2 domain)
        if (!__all(tm <= m + 8.f)) {
            float mnew = fmaxf(m, tm);
            float fsc = exp2_fast(m - mnew);
            lsum *= fsc;
            #pragma unroll
            for (int i = 0; i < 16; ++i) { o0[i] *= fsc; o1[i] *= fsc; }
            m = mnew;
        }

        // P = exp2(S - m); row-sum (tree + 1 shfl); pack to bf16 pairs (HW cvt_pk)
        #pragma unroll
        for (int i = 0; i < 16; ++i) {
            s0[i] = exp2_fast(s0[i] - m);
            s1[i] = exp2_fast(s1[i] - m);
        }
        float p8[8];
        #pragma unroll
        for (int i = 0; i < 8; ++i)
            p8[i] = (s0[i] + s0[i + 8]) + (s1[i] + s1[i + 8]);
        float psum = ((p8[0] + p8[1]) + (p8[2] + p8[3])) + ((p8[4] + p8[5]) + (p8[6] + p8[7]));
        psum += __shfl_xor(psum, 32);
        lsum += psum;

        unsigned pk0[8], pk1[8];
        #pragma unroll
        for (int p = 0; p < 8; ++p) {
            pk0[p] = cvtpk(s0[2 * p], s0[2 * p + 1]);
            pk1[p] = cvtpk(s1[2 * p], s1[2 * p + 1]);
        }

        // PV: for each 16-kv chunk c, build P^T B-fragment in-register
        // (shfl_xor lane+-32 exchange -- VERIFIED mapping) and accumulate
        // O^T (two 32-row d-tiles) over the kv dimension.
        #pragma unroll
        for (int c = 0; c < 4; ++c) {
            unsigned w0 = (c & 2) ? pk1[(c & 1) * 4 + 0] : pk0[(c & 1) * 4 + 0];
            unsigned w1 = (c & 2) ? pk1[(c & 1) * 4 + 1] : pk0[(c & 1) * 4 + 1];
            unsigned w2 = (c & 2) ? pk1[(c & 1) * 4 + 2] : pk0[(c & 1) * 4 + 2];
            unsigned w3 = (c & 2) ? pk1[(c & 1) * 4 + 3] : pk0[(c & 1) * 4 + 3];
            unsigned t0 = hi2 ? w0 : w2;
            unsigned t1 = hi2 ? w1 : w3;
            unsigned r0 = __shfl_xor(t0, 32);
            unsigned r1 = __shfl_xor(t1, 32);
            union { unsigned u[4]; bf16x8 v; } uf;
            uf.u[0] = hi2 ? r0 : w0;
            uf.u[1] = hi2 ? r1 : w1;
            uf.u[2] = hi2 ? w2 : r0;
            uf.u[3] = hi2 ? w3 : r1;
            bf16x8 pf = uf.v;

            int off = (c * 32 + hi2 * 16) ^ swz;
            bf16x8 vf0 = *(const bf16x8*)(sV + q32 * 128 + off);
            o0 = __builtin_amdgcn_mfma_f32_32x32x16_bf16(vf0, pf, o0, 0, 0, 0);
            bf16x8 vf1 = *(const bf16x8*)(sV + (32 + q32) * 128 + off);
            o1 = __builtin_amdgcn_mfma_f32_32x32x16_bf16(vf1, pf, o1, 0, 0, 0);
        }

        __syncthreads();    // DMA drained + all waves done with buf[cur]
        cur ^= 1;
    }

    const float inv = 1.f / lsum;
    const int b = bh >> 4, h = bh & 15;
    const int tq = q0 + q32;
    unsigned* aou = (unsigned*)(ao + ((size_t)(b * T_ + tq)) * D_ + h * HD_);
    #pragma unroll
    for (int pr = 0; pr < 8; ++pr) {
        int d0 = 2 * (pr & 1) + 8 * (pr >> 1) + 4 * hi2;    // even
        aou[d0 >> 1]        = cvtpk(o0[2 * pr] * inv, o0[2 * pr + 1] * inv);
        aou[(32 + d0) >> 1] = cvtpk(o1[2 * pr] * inv, o1[2 * pr + 1] * inv);
    }
}

// ---------------------------------------------------------------------------
extern "C" void kernel_launch(void* const* d_in, const int* in_sizes, int n_in,
                              void* d_out, int out_size, void* d_ws, size_t ws_size,
                              hipStream_t stream) {
    const float* x    = (const float*)d_in[0];
    const float* Wqkv = (const float*)d_in[1];
    const float* bqkv = (const float*)d_in[2];
    const float* Wout = (const float*)d_in[3];
    const float* bout = (const float*)d_in[4];
    float* out = (float*)d_out;

    char* ws = (char*)d_ws;
    short* xb  = (short*)(ws);                      // 8 MB  x bf16 [4096][1024]
    short* WqT = (short*)(ws + ((size_t)8  << 20)); // 6 MB  Wqkv^T bf16 [3072][1024]
    short* WoT = (short*)(ws + ((size_t)14 << 20)); // 2 MB  Wout^T bf16 [1024][1024]
    short* qb  = (short*)(ws + ((size_t)16 << 20)); // 8 MB  q [B*H][T][Hd]
    short* kb  = (short*)(ws + ((size_t)24 << 20)); // 8 MB  k [B*H][T][Hd]
    short* vtb = (short*)(ws + ((size_t)32 << 20)); // 8 MB  v^T [B*H][Hd][T]
    short* aob = (short*)(ws + ((size_t)40 << 20)); // 8 MB  attn out bf16 [4096][1024]

    convert_x<<<(M_TOT * D_ / 8 + 255) / 256, 256, 0, stream>>>(x, xb, M_TOT * D_ / 8);
    transpose_convert2<<<dim3(N_QKV / 64, D_ / 64, 2), 256, 0, stream>>>(
        Wqkv, WqT, Wout, WoT);

    gemm_dl<128, 128, 0><<<dim3(N_QKV / 128, M_TOT / 128), 256, 0, stream>>>(
        xb, WqT, bqkv, M_TOT, N_QKV, D_, qb, kb, vtb, nullptr);

    attn<<<dim3(B_ * H_, T_ / 256), 512, 0, stream>>>(qb, kb, vtb, aob);

    gemm_dl<128, 64, 1><<<dim3(D_ / 64, M_TOT / 128), 256, 0, stream>>>(
        aob, WoT, bout, M_TOT, D_, D_, nullptr, nullptr, nullptr, out);
}

// Round 26
// 121.337 us; speedup vs baseline: 1.1599x; 1.0159x over previous
//
#include <hip/hip_runtime.h>
#include <hip/hip_bf16.h>

#define B_   2
#define T_   2048
#define D_   1024
#define H_   16
#define HD_  64
#define M_TOT (B_*T_)    // 4096
#define N_QKV (3*D_)     // 3072

typedef __attribute__((ext_vector_type(8))) short bf16x8;
typedef __attribute__((ext_vector_type(4))) float f32x4;
typedef __attribute__((ext_vector_type(16))) float f32x16;

static __device__ __forceinline__ short f2bf(float f) {
    union { __hip_bfloat16 h; short s; } u;
    u.h = __float2bfloat16(f);
    return u.s;
}
static __device__ __forceinline__ unsigned pack2(float a, float b) {
    return (unsigned)(unsigned short)f2bf(a) | ((unsigned)(unsigned short)f2bf(b) << 16);
}
// HW packed f32->bf16 (RNE): D.lo16 = bf16(lo), D.hi16 = bf16(hi). 1 VALU op.
static __device__ __forceinline__ unsigned cvtpk(float lo, float hi) {
    unsigned r;
    asm("v_cvt_pk_bf16_f32 %0, %1, %2" : "=v"(r) : "v"(lo), "v"(hi));
    return r;
}
static __device__ __forceinline__ float exp2_fast(float x) {
    return __builtin_amdgcn_exp2f(x);
}
static __device__ __forceinline__ f32x16 zero16() {
    f32x16 z;
    #pragma unroll
    for (int i = 0; i < 16; ++i) z[i] = 0.f;
    return z;
}
// async global->LDS DMA, 16B per lane. LDS dest = wave-uniform base + lane*16.
static __device__ __forceinline__ void gload16(const void* g, void* l) {
    __builtin_amdgcn_global_load_lds(
        (__attribute__((address_space(1))) unsigned int*)(unsigned long long)g,
        (__attribute__((address_space(3))) unsigned int*)l, 16, 0, 0);
}
// Session ledger: (R9-R12) permlane32_swap failed 2x2 factorial -> shfl_xor
// PV (verified). (R14) counted-vmcnt in attn neutral. (R16) T15 regressed.
// (R17) depth-2 GEMM prefetch neutral (kept). (R18/R19) KV split-K net
// negative. (R20) bh-major attn grid: FETCH 69.7->12.3MB (kept). (R21)
// cvt_pk P-pack -3us (kept). (R22) setprio regressed. (R23) KVBLK=128
// neutral. (R24) 4-wave dedup regressed (needs exactly 2 waves/SIMD).
// (R25) fused weight-transpose launch (kept, total 123.3).
// R26: XCD-colocate out-proj by A-panel -- grid axes swapped for MODE==1
// (flat%8 = m-tile%8 since gridX=32), so all 16 n-blocks sharing one
// 256KB aob panel land on one XCD's L2 (R20's verified mechanism).

// ---------------------------------------------------------------------------
// x fp32 -> bf16, straight copy (8 elems/thread)
__global__ __launch_bounds__(256) void convert_x(const float* __restrict__ x,
                                                 short* __restrict__ xb, int n8) {
    int i = blockIdx.x * blockDim.x + threadIdx.x;
    if (i >= n8) return;
    const float4* p = (const float4*)x + (size_t)i * 2;
    float4 a = p[0], b = p[1];
    bf16x8 o;
    o[0]=f2bf(a.x); o[1]=f2bf(a.y); o[2]=f2bf(a.z); o[3]=f2bf(a.w);
    o[4]=f2bf(b.x); o[5]=f2bf(b.y); o[6]=f2bf(b.z); o[7]=f2bf(b.w);
    *((bf16x8*)xb + i) = o;
}

// Fused weight transpose+convert: z==0 -> Wqkv[1024][3072] -> WqT[3072][1024];
// z==1 -> Wout[1024][1024] -> WoT[1024][1024]. K=1024 both. 64x64 LDS tiles.
// z==1 blocks with bx>=16 early-return (block-uniform, before any barrier).
__global__ __launch_bounds__(256)
void transpose_convert2(const float* __restrict__ in0, short* __restrict__ out0,
                        const float* __restrict__ in1, short* __restrict__ out1) {
    const float* in; short* out; int N;
    if (blockIdx.z == 0) { in = in0; out = out0; N = N_QKV; }
    else {
        if (blockIdx.x >= 16) return;
        in = in1; out = out1; N = D_;
    }
    __shared__ short tile[64][65];
    int k0 = blockIdx.y * 64, n0 = blockIdx.x * 64;
    int t = threadIdx.x;
    #pragma unroll
    for (int i = 0; i < 16; ++i) {
        int idx = i * 256 + t;
        int r = idx >> 6, c = idx & 63;
        tile[r][c] = f2bf(in[(size_t)(k0 + r) * N + n0 + c]);
    }
    __syncthreads();
    #pragma unroll
    for (int i = 0; i < 16; ++i) {
        int idx = i * 256 + t;
        int r = idx >> 6, c = idx & 63;     // r: n-local, c: k-local
        out[(size_t)(n0 + r) * D_ + k0 + c] = tile[c][r];
    }
}

// ---------------------------------------------------------------------------
// BK=32 GEMM with depth-2 prefetch (R17-verified). C = A*BT^T + bias.
// MODE==1 (out-proj): grid axes swapped (x=m-tile, y=n-tile) so XCD=m%8
// colocates blocks sharing one A-panel (R26).
#define QSC 0.18033688f   // 0.125 * log2(e)
template<int BM, int BN, int MODE>
__global__ __launch_bounds__(256)
void gemm_dl(const short* __restrict__ A, const short* __restrict__ BT,
             const float* __restrict__ bias, int M, int N, int K,
             short* __restrict__ qo, short* __restrict__ ko,
             short* __restrict__ vo, float* __restrict__ fo) {
    constexpr int BUF = (BM + BN) * 64;        // bytes per stage buffer (64B rows)
    constexpr int NL = (BM + BN) / 64;         // DMA instrs per thread per stage
    __shared__ char smem[3 * BUF];
    const int t = threadIdx.x, w = t >> 6, l = t & 63;
    const int qi_l = l & 15, hi_l = l >> 4;
    const int m0 = (MODE == 1 ? blockIdx.x : blockIdx.y) * BM;
    const int n0 = (MODE == 1 ? blockIdx.y : blockIdx.x) * BN;
    const int wr = w >> 1, wc = w & 1;
    constexpr int MI = BM / 32, NI = BN / 32;

    f32x4 acc[MI][NI];
    #pragma unroll
    for (int mi = 0; mi < MI; ++mi)
        #pragma unroll
        for (int ni = 0; ni < NI; ++ni)
            acc[mi][ni] = (f32x4){0.f, 0.f, 0.f, 0.f};

    const int lrow = l >> 2;                     // 0..15 rows within one 1KB DMA
    const int lch  = ((l & 3) ^ (lrow & 3)) * 8; // pre-swizzled source chunk (elems)

    auto stage = [&](char* dst, int k0) {
        #pragma unroll
        for (int i = 0; i < BM / 64; ++i) {
            int rb = w * (BM / 4) + i * 16;
            gload16(A + (size_t)(m0 + rb + lrow) * K + k0 + lch, dst + rb * 64);
        }
        #pragma unroll
        for (int i = 0; i < BN / 64; ++i) {
            int rb = w * (BN / 4) + i * 16;
            gload16(BT + (size_t)(n0 + rb + lrow) * K + k0 + lch, dst + BM * 64 + rb * 64);
        }
    };

    const int nt = K / 32;
    stage(smem, 0);
    if (nt > 1) stage(smem + BUF, 32);
    for (int it = 0; it < nt; ++it) {
        if (it + 2 < nt) {
            stage(smem + ((it + 2) % 3) * BUF, (it + 2) * 32);  // t+2 in flight
            if constexpr (NL == 4)      asm volatile("s_waitcnt vmcnt(8)" ::: "memory");
            else if constexpr (NL == 3) asm volatile("s_waitcnt vmcnt(6)" ::: "memory");
            else                        asm volatile("s_waitcnt vmcnt(0)" ::: "memory");
        } else if (it + 1 < nt) {
            if constexpr (NL == 4)      asm volatile("s_waitcnt vmcnt(4)" ::: "memory");
            else if constexpr (NL == 3) asm volatile("s_waitcnt vmcnt(3)" ::: "memory");
            else                        asm volatile("s_waitcnt vmcnt(0)" ::: "memory");
        } else {
            asm volatile("s_waitcnt vmcnt(0)" ::: "memory");
        }
        __builtin_amdgcn_s_barrier();    // B1: tile t visible to all waves

        char* sA = smem + (it % 3) * BUF;
        char* sB = sA + BM * 64;
        bf16x8 af[MI], bfr[NI];
        #pragma unroll
        for (int mi = 0; mi < MI; ++mi) {
            int row = wr * (BM / 2) + mi * 16 + qi_l;
            int ad = row * 64 + ((hi_l ^ (row & 3)) * 16);
            af[mi] = *(const bf16x8*)(sA + ad);
        }
        #pragma unroll
        for (int ni = 0; ni < NI; ++ni) {
            int row = wc * (BN / 2) + ni * 16 + qi_l;
            int ad = row * 64 + ((hi_l ^ (row & 3)) * 16);
            bfr[ni] = *(const bf16x8*)(sB + ad);
        }
        #pragma unroll
        for (int mi = 0; mi < MI; ++mi)
            #pragma unroll
            for (int ni = 0; ni < NI; ++ni)
                acc[mi][ni] = __builtin_amdgcn_mfma_f32_16x16x32_bf16(af[mi], bfr[ni], acc[mi][ni], 0, 0, 0);

        __builtin_amdgcn_s_barrier();    // B2: buf[it%3] reads done
    }

    #pragma unroll
    for (int mi = 0; mi < MI; ++mi) {
        int rbase = m0 + wr * (BM / 2) + mi * 16 + 4 * hi_l;
        #pragma unroll
        for (int ni = 0; ni < NI; ++ni) {
            int n = n0 + wc * (BN / 2) + ni * 16 + qi_l;
            float bv = bias[n];
            #pragma unroll
            for (int r = 0; r < 4; ++r) {
                int mm = rbase + r;
                float c = acc[mi][ni][r] + bv;
                if (MODE == 0) {
                    int which = n >> 10, rest = n & 1023;
                    int h = rest >> 6, d = rest & 63;
                    int b = mm >> 11, tq = mm & 2047;
                    size_t bh = (size_t)(b * H_ + h);
                    if (which == 0)      qo[(bh * T_ + tq) * HD_ + d] = f2bf(c * QSC);
                    else if (which == 1) ko[(bh * T_ + tq) * HD_ + d] = f2bf(c);
                    else                 vo[(bh * HD_ + d) * T_ + tq] = f2bf(c);
                } else {
                    fo[(size_t)mm * N + n] = c;
                }
            }
        }
    }
}

// ---------------------------------------------------------------------------
// Flash attention (best verified: R21 body): bh-major grid (XCD=bh%8 L2
// locality), 8 waves x 32 q-rows (QBLK=256), KVBLK=64, swapped 32x32 MFMA,
// HW cvt_pk P-pack, shfl_xor PV redistribution, cvtpk epilogue.
// q,k: [B*H, T, Hd] bf16 (q pre-scaled by 1/8*log2e); vt: [B*H, Hd, T] bf16.
__global__ __launch_bounds__(512)
void attn(const short* __restrict__ q, const short* __restrict__ k,
          const short* __restrict__ vt, short* __restrict__ ao) {
    __shared__ char smem[32768];   // buf0: K@0 V@8192; buf1: K@16384 V@24576

    const int t = threadIdx.x, w = t >> 6, l = t & 63;
    const int q32 = l & 31, hi2 = l >> 5;
    const int swz = (l & 7) << 4;
    const int bh = blockIdx.x;                     // bh on x: XCD = bh % 8
    const int q0 = blockIdx.y * 256 + w * 32;      // q-tile on y

    const short* qptr = q + ((size_t)bh * T_ + q0) * HD_;
    const short* kbase = k + (size_t)bh * T_ * HD_;
    const short* vbase = vt + (size_t)bh * HD_ * T_;

    const int srow = w * 8 + (l >> 3);              // staging row (this wave: 8 rows)
    const int sch  = ((l & 7) ^ (l >> 3)) * 8;      // pre-swizzled source chunk

    // Q fragments: B-operand of 32x32x16: lane holds Q[q=q32][d = kc*16 + hi2*8 + j]
    bf16x8 qa[4];
    #pragma unroll
    for (int kc = 0; kc < 4; ++kc)
        qa[kc] = *(const bf16x8*)(qptr + q32 * HD_ + kc * 16 + hi2 * 8);

    f32x16 o0 = zero16(), o1 = zero16();
    float m = -1e30f, lsum = 0.f;

    // prologue: stage tile 0 into buf 0 (1 K + 1 V DMA per thread)
    gload16(kbase + (size_t)srow * HD_ + sch, smem + srow * 128);
    gload16(vbase + (size_t)srow * T_ + sch,  smem + 8192 + srow * 128);
    __syncthreads();

    int cur = 0;
    for (int kb = 0; kb < T_; kb += 64) {
        char* sK = smem + cur * 16384;
        char* sV = sK + 8192;
        if (kb + 64 < T_) {
            char* nK = smem + (cur ^ 1) * 16384;
            gload16(kbase + (size_t)(kb + 64 + srow) * HD_ + sch, nK + srow * 128);
            gload16(vbase + (size_t)srow * T_ + (kb + 64) + sch,  nK + 8192 + srow * 128);
        }

        // S^T: two 32x32 tiles (kvt=0,1), accumulate over Hd in 4 chunks of 16
        f32x16 s0 = zero16(), s1 = zero16();
        #pragma unroll
        for (int kc = 0; kc < 4; ++kc) {
            int off = (kc * 32 + hi2 * 16) ^ swz;
            bf16x8 kf0 = *(const bf16x8*)(sK + q32 * 128 + off);
            s0 = __builtin_amdgcn_mfma_f32_32x32x16_bf16(kf0, qa[kc], s0, 0, 0, 0);
            bf16x8 kf1 = *(const bf16x8*)(sK + (32 + q32) * 128 + off);
            s1 = __builtin_amdgcn_mfma_f32_32x32x16_bf16(kf1, qa[kc], s1, 0, 0, 0);
        }

        // row max: 32 in-lane (tree) + 1 exchange with lane^32
        float a8[8];
        #pragma unroll
        for (int i = 0; i < 8; ++i)
            a8[i] = fmaxf(fmaxf(s0[i], s0[i + 8]), fmaxf(s1[i], s1[i + 8]));
        float b4_0 = fmaxf(a8[0], a8[1]), b4_1 = fmaxf(a8[2], a8[3]);
        float b4_2 = fmaxf(a8[4], a8[5]), b4_3 = fmaxf(a8[6], a8[7]);
        float tm = fmaxf(fmaxf(b4_0, b4_1), fmaxf(b4_2, b4_3));
        tm = fmaxf(tm, __shfl_xor(tm, 32));

        // defer-max (T13): skip O-rescale when max growth <= 8 (log2 domain)
        if (!__all(tm <= m + 8.f)) {
            float mnew = fmaxf(m, tm);
            float fsc = exp2_fast(m - mnew);
            lsum *= fsc;
            #pragma unroll
            for (int i = 0; i < 16; ++i) { o0[i] *= fsc; o1[i] *= fsc; }
            m = mnew;
        }

        // P = exp2(S - m); row-sum (tree + 1 shfl); pack to bf16 pairs (HW cvt_pk)
        #pragma unroll
        for (int i = 0; i < 16; ++i) {
            s0[i] = exp2_fast(s0[i] - m);
            s1[i] = exp2_fast(s1[i] - m);
        }
        float p8[8];
        #pragma unroll
        for (int i = 0; i < 8; ++i)
            p8[i] = (s0[i] + s0[i + 8]) + (s1[i] + s1[i + 8]);
        float psum = ((p8[0] + p8[1]) + (p8[2] + p8[3])) + ((p8[4] + p8[5]) + (p8[6] + p8[7]));
        psum += __shfl_xor(psum, 32);
        lsum += psum;

        unsigned pk0[8], pk1[8];
        #pragma unroll
        for (int p = 0; p < 8; ++p) {
            pk0[p] = cvtpk(s0[2 * p], s0[2 * p + 1]);
            pk1[p] = cvtpk(s1[2 * p], s1[2 * p + 1]);
        }

        // PV: for each 16-kv chunk c, build P^T B-fragment in-register
        // (shfl_xor lane+-32 exchange -- VERIFIED mapping) and accumulate
        // O^T (two 32-row d-tiles) over the kv dimension.
        #pragma unroll
        for (int c = 0; c < 4; ++c) {
            unsigned w0 = (c & 2) ? pk1[(c & 1) * 4 + 0] : pk0[(c & 1) * 4 + 0];
            unsigned w1 = (c & 2) ? pk1[(c & 1) * 4 + 1] : pk0[(c & 1) * 4 + 1];
            unsigned w2 = (c & 2) ? pk1[(c & 1) * 4 + 2] : pk0[(c & 1) * 4 + 2];
            unsigned w3 = (c & 2) ? pk1[(c & 1) * 4 + 3] : pk0[(c & 1) * 4 + 3];
            unsigned t0 = hi2 ? w0 : w2;
            unsigned t1 = hi2 ? w1 : w3;
            unsigned r0 = __shfl_xor(t0, 32);
            unsigned r1 = __shfl_xor(t1, 32);
            union { unsigned u[4]; bf16x8 v; } uf;
            uf.u[0] = hi2 ? r0 : w0;
            uf.u[1] = hi2 ? r1 : w1;
            uf.u[2] = hi2 ? w2 : r0;
            uf.u[3] = hi2 ? w3 : r1;
            bf16x8 pf = uf.v;

            int off = (c * 32 + hi2 * 16) ^ swz;
            bf16x8 vf0 = *(const bf16x8*)(sV + q32 * 128 + off);
            o0 = __builtin_amdgcn_mfma_f32_32x32x16_bf16(vf0, pf, o0, 0, 0, 0);
            bf16x8 vf1 = *(const bf16x8*)(sV + (32 + q32) * 128 + off);
            o1 = __builtin_amdgcn_mfma_f32_32x32x16_bf16(vf1, pf, o1, 0, 0, 0);
        }

        __syncthreads();    // DMA drained + all waves done with buf[cur]
        cur ^= 1;
    }

    const float inv = 1.f / lsum;
    const int b = bh >> 4, h = bh & 15;
    const int tq = q0 + q32;
    unsigned* aou = (unsigned*)(ao + ((size_t)(b * T_ + tq)) * D_ + h * HD_);
    #pragma unroll
    for (int pr = 0; pr < 8; ++pr) {
        int d0 = 2 * (pr & 1) + 8 * (pr >> 1) + 4 * hi2;    // even
        aou[d0 >> 1]        = cvtpk(o0[2 * pr] * inv, o0[2 * pr + 1] * inv);
        aou[(32 + d0) >> 1] = cvtpk(o1[2 * pr] * inv, o1[2 * pr + 1] * inv);
    }
}

// ---------------------------------------------------------------------------
extern "C" void kernel_launch(void* const* d_in, const int* in_sizes, int n_in,
                              void* d_out, int out_size, void* d_ws, size_t ws_size,
                              hipStream_t stream) {
    const float* x    = (const float*)d_in[0];
    const float* Wqkv = (const float*)d_in[1];
    const float* bqkv = (const float*)d_in[2];
    const float* Wout = (const float*)d_in[3];
    const float* bout = (const float*)d_in[4];
    float* out = (float*)d_out;

    char* ws = (char*)d_ws;
    short* xb  = (short*)(ws);                      // 8 MB  x bf16 [4096][1024]
    short* WqT = (short*)(ws + ((size_t)8  << 20)); // 6 MB  Wqkv^T bf16 [3072][1024]
    short* WoT = (short*)(ws + ((size_t)14 << 20)); // 2 MB  Wout^T bf16 [1024][1024]
    short* qb  = (short*)(ws + ((size_t)16 << 20)); // 8 MB  q [B*H][T][Hd]
    short* kb  = (short*)(ws + ((size_t)24 << 20)); // 8 MB  k [B*H][T][Hd]
    short* vtb = (short*)(ws + ((size_t)32 << 20)); // 8 MB  v^T [B*H][Hd][T]
    short* aob = (short*)(ws + ((size_t)40 << 20)); // 8 MB  attn out bf16 [4096][1024]

    convert_x<<<(M_TOT * D_ / 8 + 255) / 256, 256, 0, stream>>>(x, xb, M_TOT * D_ / 8);
    transpose_convert2<<<dim3(N_QKV / 64, D_ / 64, 2), 256, 0, stream>>>(
        Wqkv, WqT, Wout, WoT);

    gemm_dl<128, 128, 0><<<dim3(N_QKV / 128, M_TOT / 128), 256, 0, stream>>>(
        xb, WqT, bqkv, M_TOT, N_QKV, D_, qb, kb, vtb, nullptr);

    attn<<<dim3(B_ * H_, T_ / 256), 512, 0, stream>>>(qb, kb, vtb, aob);

    // R26: x = m-tile (32), y = n-tile (16) -> XCD = m%8 colocates A-panels
    gemm_dl<128, 64, 1><<<dim3(M_TOT / 128, D_ / 64), 256, 0, stream>>>(
        aob, WoT, bout, M_TOT, D_, D_, nullptr, nullptr, nullptr, out);
}

// Round 27
// 120.632 us; speedup vs baseline: 1.1667x; 1.0058x over previous
//
#include <hip/hip_runtime.h>
#include <hip/hip_bf16.h>

#define B_   2
#define T_   2048
#define D_   1024
#define H_   16
#define HD_  64
#define M_TOT (B_*T_)    // 4096
#define N_QKV (3*D_)     // 3072

typedef __attribute__((ext_vector_type(8))) short bf16x8;
typedef __attribute__((ext_vector_type(4))) float f32x4;
typedef __attribute__((ext_vector_type(16))) float f32x16;

static __device__ __forceinline__ short f2bf(float f) {
    union { __hip_bfloat16 h; short s; } u;
    u.h = __float2bfloat16(f);
    return u.s;
}
static __device__ __forceinline__ unsigned pack2(float a, float b) {
    return (unsigned)(unsigned short)f2bf(a) | ((unsigned)(unsigned short)f2bf(b) << 16);
}
// HW packed f32->bf16 (RNE): D.lo16 = bf16(lo), D.hi16 = bf16(hi). 1 VALU op.
static __device__ __forceinline__ unsigned cvtpk(float lo, float hi) {
    unsigned r;
    asm("v_cvt_pk_bf16_f32 %0, %1, %2" : "=v"(r) : "v"(lo), "v"(hi));
    return r;
}
static __device__ __forceinline__ float exp2_fast(float x) {
    return __builtin_amdgcn_exp2f(x);
}
static __device__ __forceinline__ f32x16 zero16() {
    f32x16 z;
    #pragma unroll
    for (int i = 0; i < 16; ++i) z[i] = 0.f;
    return z;
}
// async global->LDS DMA, 16B per lane. LDS dest = wave-uniform base + lane*16.
static __device__ __forceinline__ void gload16(const void* g, void* l) {
    __builtin_amdgcn_global_load_lds(
        (__attribute__((address_space(1))) unsigned int*)(unsigned long long)g,
        (__attribute__((address_space(3))) unsigned int*)l, 16, 0, 0);
}
// Session ledger: (R9-R12) permlane32_swap failed 2x2 factorial -> shfl_xor
// PV (verified). (R14) counted-vmcnt in attn neutral. (R16) T15 regressed.
// (R17) depth-2 GEMM prefetch neutral (kept). (R18/R19) KV split-K net
// negative. (R20) bh-major attn grid: FETCH 69.7->12.3MB (kept). (R21)
// cvt_pk P-pack -3us (kept). (R22) setprio regressed. (R23) KVBLK=128
// neutral. (R24) 4-wave dedup regressed (needs exactly 2 waves/SIMD).
// (R25) fused weight-transpose (kept). (R26) out-proj A-panel colocation
// -2us (kept, total 121.3). R27: same A-panel colocation for QKV GEMM
// (grid (32,24): XCD = m-tile%8; QKV FETCH was 40MB vs 14MB compulsory).

// ---------------------------------------------------------------------------
// x fp32 -> bf16, straight copy (8 elems/thread)
__global__ __launch_bounds__(256) void convert_x(const float* __restrict__ x,
                                                 short* __restrict__ xb, int n8) {
    int i = blockIdx.x * blockDim.x + threadIdx.x;
    if (i >= n8) return;
    const float4* p = (const float4*)x + (size_t)i * 2;
    float4 a = p[0], b = p[1];
    bf16x8 o;
    o[0]=f2bf(a.x); o[1]=f2bf(a.y); o[2]=f2bf(a.z); o[3]=f2bf(a.w);
    o[4]=f2bf(b.x); o[5]=f2bf(b.y); o[6]=f2bf(b.z); o[7]=f2bf(b.w);
    *((bf16x8*)xb + i) = o;
}

// Fused weight transpose+convert: z==0 -> Wqkv[1024][3072] -> WqT[3072][1024];
// z==1 -> Wout[1024][1024] -> WoT[1024][1024]. K=1024 both. 64x64 LDS tiles.
// z==1 blocks with bx>=16 early-return (block-uniform, before any barrier).
__global__ __launch_bounds__(256)
void transpose_convert2(const float* __restrict__ in0, short* __restrict__ out0,
                        const float* __restrict__ in1, short* __restrict__ out1) {
    const float* in; short* out; int N;
    if (blockIdx.z == 0) { in = in0; out = out0; N = N_QKV; }
    else {
        if (blockIdx.x >= 16) return;
        in = in1; out = out1; N = D_;
    }
    __shared__ short tile[64][65];
    int k0 = blockIdx.y * 64, n0 = blockIdx.x * 64;
    int t = threadIdx.x;
    #pragma unroll
    for (int i = 0; i < 16; ++i) {
        int idx = i * 256 + t;
        int r = idx >> 6, c = idx & 63;
        tile[r][c] = f2bf(in[(size_t)(k0 + r) * N + n0 + c]);
    }
    __syncthreads();
    #pragma unroll
    for (int i = 0; i < 16; ++i) {
        int idx = i * 256 + t;
        int r = idx >> 6, c = idx & 63;     // r: n-local, c: k-local
        out[(size_t)(n0 + r) * D_ + k0 + c] = tile[c][r];
    }
}

// ---------------------------------------------------------------------------
// BK=32 GEMM with depth-2 prefetch (R17-verified). C = A*BT^T + bias.
// SWAP==1: grid axes swapped (x=m-tile, y=n-tile) so XCD=m%8 colocates
// blocks sharing one A-panel (R26/R27; requires gridX % 8 == 0).
#define QSC 0.18033688f   // 0.125 * log2(e)
template<int BM, int BN, int MODE, int SWAP>
__global__ __launch_bounds__(256)
void gemm_dl(const short* __restrict__ A, const short* __restrict__ BT,
             const float* __restrict__ bias, int M, int N, int K,
             short* __restrict__ qo, short* __restrict__ ko,
             short* __restrict__ vo, float* __restrict__ fo) {
    constexpr int BUF = (BM + BN) * 64;        // bytes per stage buffer (64B rows)
    constexpr int NL = (BM + BN) / 64;         // DMA instrs per thread per stage
    __shared__ char smem[3 * BUF];
    const int t = threadIdx.x, w = t >> 6, l = t & 63;
    const int qi_l = l & 15, hi_l = l >> 4;
    const int m0 = (SWAP ? blockIdx.x : blockIdx.y) * BM;
    const int n0 = (SWAP ? blockIdx.y : blockIdx.x) * BN;
    const int wr = w >> 1, wc = w & 1;
    constexpr int MI = BM / 32, NI = BN / 32;

    f32x4 acc[MI][NI];
    #pragma unroll
    for (int mi = 0; mi < MI; ++mi)
        #pragma unroll
        for (int ni = 0; ni < NI; ++ni)
            acc[mi][ni] = (f32x4){0.f, 0.f, 0.f, 0.f};

    const int lrow = l >> 2;                     // 0..15 rows within one 1KB DMA
    const int lch  = ((l & 3) ^ (lrow & 3)) * 8; // pre-swizzled source chunk (elems)

    auto stage = [&](char* dst, int k0) {
        #pragma unroll
        for (int i = 0; i < BM / 64; ++i) {
            int rb = w * (BM / 4) + i * 16;
            gload16(A + (size_t)(m0 + rb + lrow) * K + k0 + lch, dst + rb * 64);
        }
        #pragma unroll
        for (int i = 0; i < BN / 64; ++i) {
            int rb = w * (BN / 4) + i * 16;
            gload16(BT + (size_t)(n0 + rb + lrow) * K + k0 + lch, dst + BM * 64 + rb * 64);
        }
    };

    const int nt = K / 32;
    stage(smem, 0);
    if (nt > 1) stage(smem + BUF, 32);
    for (int it = 0; it < nt; ++it) {
        if (it + 2 < nt) {
            stage(smem + ((it + 2) % 3) * BUF, (it + 2) * 32);  // t+2 in flight
            if constexpr (NL == 4)      asm volatile("s_waitcnt vmcnt(8)" ::: "memory");
            else if constexpr (NL == 3) asm volatile("s_waitcnt vmcnt(6)" ::: "memory");
            else                        asm volatile("s_waitcnt vmcnt(0)" ::: "memory");
        } else if (it + 1 < nt) {
            if constexpr (NL == 4)      asm volatile("s_waitcnt vmcnt(4)" ::: "memory");
            else if constexpr (NL == 3) asm volatile("s_waitcnt vmcnt(3)" ::: "memory");
            else                        asm volatile("s_waitcnt vmcnt(0)" ::: "memory");
        } else {
            asm volatile("s_waitcnt vmcnt(0)" ::: "memory");
        }
        __builtin_amdgcn_s_barrier();    // B1: tile t visible to all waves

        char* sA = smem + (it % 3) * BUF;
        char* sB = sA + BM * 64;
        bf16x8 af[MI], bfr[NI];
        #pragma unroll
        for (int mi = 0; mi < MI; ++mi) {
            int row = wr * (BM / 2) + mi * 16 + qi_l;
            int ad = row * 64 + ((hi_l ^ (row & 3)) * 16);
            af[mi] = *(const bf16x8*)(sA + ad);
        }
        #pragma unroll
        for (int ni = 0; ni < NI; ++ni) {
            int row = wc * (BN / 2) + ni * 16 + qi_l;
            int ad = row * 64 + ((hi_l ^ (row & 3)) * 16);
            bfr[ni] = *(const bf16x8*)(sB + ad);
        }
        #pragma unroll
        for (int mi = 0; mi < MI; ++mi)
            #pragma unroll
            for (int ni = 0; ni < NI; ++ni)
                acc[mi][ni] = __builtin_amdgcn_mfma_f32_16x16x32_bf16(af[mi], bfr[ni], acc[mi][ni], 0, 0, 0);

        __builtin_amdgcn_s_barrier();    // B2: buf[it%3] reads done
    }

    #pragma unroll
    for (int mi = 0; mi < MI; ++mi) {
        int rbase = m0 + wr * (BM / 2) + mi * 16 + 4 * hi_l;
        #pragma unroll
        for (int ni = 0; ni < NI; ++ni) {
            int n = n0 + wc * (BN / 2) + ni * 16 + qi_l;
            float bv = bias[n];
            #pragma unroll
            for (int r = 0; r < 4; ++r) {
                int mm = rbase + r;
                float c = acc[mi][ni][r] + bv;
                if (MODE == 0) {
                    int which = n >> 10, rest = n & 1023;
                    int h = rest >> 6, d = rest & 63;
                    int b = mm >> 11, tq = mm & 2047;
                    size_t bh = (size_t)(b * H_ + h);
                    if (which == 0)      qo[(bh * T_ + tq) * HD_ + d] = f2bf(c * QSC);
                    else if (which == 1) ko[(bh * T_ + tq) * HD_ + d] = f2bf(c);
                    else                 vo[(bh * HD_ + d) * T_ + tq] = f2bf(c);
                } else {
                    fo[(size_t)mm * N + n] = c;
                }
            }
        }
    }
}

// ---------------------------------------------------------------------------
// Flash attention (best verified: R21 body): bh-major grid (XCD=bh%8 L2
// locality), 8 waves x 32 q-rows (QBLK=256), KVBLK=64, swapped 32x32 MFMA,
// HW cvt_pk P-pack, shfl_xor PV redistribution, cvtpk epilogue.
// q,k: [B*H, T, Hd] bf16 (q pre-scaled by 1/8*log2e); vt: [B*H, Hd, T] bf16.
__global__ __launch_bounds__(512)
void attn(const short* __restrict__ q, const short* __restrict__ k,
          const short* __restrict__ vt, short* __restrict__ ao) {
    __shared__ char smem[32768];   // buf0: K@0 V@8192; buf1: K@16384 V@24576

    const int t = threadIdx.x, w = t >> 6, l = t & 63;
    const int q32 = l & 31, hi2 = l >> 5;
    const int swz = (l & 7) << 4;
    const int bh = blockIdx.x;                     // bh on x: XCD = bh % 8
    const int q0 = blockIdx.y * 256 + w * 32;      // q-tile on y

    const short* qptr = q + ((size_t)bh * T_ + q0) * HD_;
    const short* kbase = k + (size_t)bh * T_ * HD_;
    const short* vbase = vt + (size_t)bh * HD_ * T_;

    const int srow = w * 8 + (l >> 3);              // staging row (this wave: 8 rows)
    const int sch  = ((l & 7) ^ (l >> 3)) * 8;      // pre-swizzled source chunk

    // Q fragments: B-operand of 32x32x16: lane holds Q[q=q32][d = kc*16 + hi2*8 + j]
    bf16x8 qa[4];
    #pragma unroll
    for (int kc = 0; kc < 4; ++kc)
        qa[kc] = *(const bf16x8*)(qptr + q32 * HD_ + kc * 16 + hi2 * 8);

    f32x16 o0 = zero16(), o1 = zero16();
    float m = -1e30f, lsum = 0.f;

    // prologue: stage tile 0 into buf 0 (1 K + 1 V DMA per thread)
    gload16(kbase + (size_t)srow * HD_ + sch, smem + srow * 128);
    gload16(vbase + (size_t)srow * T_ + sch,  smem + 8192 + srow * 128);
    __syncthreads();

    int cur = 0;
    for (int kb = 0; kb < T_; kb += 64) {
        char* sK = smem + cur * 16384;
        char* sV = sK + 8192;
        if (kb + 64 < T_) {
            char* nK = smem + (cur ^ 1) * 16384;
            gload16(kbase + (size_t)(kb + 64 + srow) * HD_ + sch, nK + srow * 128);
            gload16(vbase + (size_t)srow * T_ + (kb + 64) + sch,  nK + 8192 + srow * 128);
        }

        // S^T: two 32x32 tiles (kvt=0,1), accumulate over Hd in 4 chunks of 16
        f32x16 s0 = zero16(), s1 = zero16();
        #pragma unroll
        for (int kc = 0; kc < 4; ++kc) {
            int off = (kc * 32 + hi2 * 16) ^ swz;
            bf16x8 kf0 = *(const bf16x8*)(sK + q32 * 128 + off);
            s0 = __builtin_amdgcn_mfma_f32_32x32x16_bf16(kf0, qa[kc], s0, 0, 0, 0);
            bf16x8 kf1 = *(const bf16x8*)(sK + (32 + q32) * 128 + off);
            s1 = __builtin_amdgcn_mfma_f32_32x32x16_bf16(kf1, qa[kc], s1, 0, 0, 0);
        }

        // row max: 32 in-lane (tree) + 1 exchange with lane^32
        float a8[8];
        #pragma unroll
        for (int i = 0; i < 8; ++i)
            a8[i] = fmaxf(fmaxf(s0[i], s0[i + 8]), fmaxf(s1[i], s1[i + 8]));
        float b4_0 = fmaxf(a8[0], a8[1]), b4_1 = fmaxf(a8[2], a8[3]);
        float b4_2 = fmaxf(a8[4], a8[5]), b4_3 = fmaxf(a8[6], a8[7]);
        float tm = fmaxf(fmaxf(b4_0, b4_1), fmaxf(b4_2, b4_3));
        tm = fmaxf(tm, __shfl_xor(tm, 32));

        // defer-max (T13): skip O-rescale when max growth <= 8 (log2 domain)
        if (!__all(tm <= m + 8.f)) {
            float mnew = fmaxf(m, tm);
            float fsc = exp2_fast(m - mnew);
            lsum *= fsc;
            #pragma unroll
            for (int i = 0; i < 16; ++i) { o0[i] *= fsc; o1[i] *= fsc; }
            m = mnew;
        }

        // P = exp2(S - m); row-sum (tree + 1 shfl); pack to bf16 pairs (HW cvt_pk)
        #pragma unroll
        for (int i = 0; i < 16; ++i) {
            s0[i] = exp2_fast(s0[i] - m);
            s1[i] = exp2_fast(s1[i] - m);
        }
        float p8[8];
        #pragma unroll
        for (int i = 0; i < 8; ++i)
            p8[i] = (s0[i] + s0[i + 8]) + (s1[i] + s1[i + 8]);
        float psum = ((p8[0] + p8[1]) + (p8[2] + p8[3])) + ((p8[4] + p8[5]) + (p8[6] + p8[7]));
        psum += __shfl_xor(psum, 32);
        lsum += psum;

        unsigned pk0[8], pk1[8];
        #pragma unroll
        for (int p = 0; p < 8; ++p) {
            pk0[p] = cvtpk(s0[2 * p], s0[2 * p + 1]);
            pk1[p] = cvtpk(s1[2 * p], s1[2 * p + 1]);
        }

        // PV: for each 16-kv chunk c, build P^T B-fragment in-register
        // (shfl_xor lane+-32 exchange -- VERIFIED mapping) and accumulate
        // O^T (two 32-row d-tiles) over the kv dimension.
        #pragma unroll
        for (int c = 0; c < 4; ++c) {
            unsigned w0 = (c & 2) ? pk1[(c & 1) * 4 + 0] : pk0[(c & 1) * 4 + 0];
            unsigned w1 = (c & 2) ? pk1[(c & 1) * 4 + 1] : pk0[(c & 1) * 4 + 1];
            unsigned w2 = (c & 2) ? pk1[(c & 1) * 4 + 2] : pk0[(c & 1) * 4 + 2];
            unsigned w3 = (c & 2) ? pk1[(c & 1) * 4 + 3] : pk0[(c & 1) * 4 + 3];
            unsigned t0 = hi2 ? w0 : w2;
            unsigned t1 = hi2 ? w1 : w3;
            unsigned r0 = __shfl_xor(t0, 32);
            unsigned r1 = __shfl_xor(t1, 32);
            union { unsigned u[4]; bf16x8 v; } uf;
            uf.u[0] = hi2 ? r0 : w0;
            uf.u[1] = hi2 ? r1 : w1;
            uf.u[2] = hi2 ? w2 : r0;
            uf.u[3] = hi2 ? w3 : r1;
            bf16x8 pf = uf.v;

            int off = (c * 32 + hi2 * 16) ^ swz;
            bf16x8 vf0 = *(const bf16x8*)(sV + q32 * 128 + off);
            o0 = __builtin_amdgcn_mfma_f32_32x32x16_bf16(vf0, pf, o0, 0, 0, 0);
            bf16x8 vf1 = *(const bf16x8*)(sV + (32 + q32) * 128 + off);
            o1 = __builtin_amdgcn_mfma_f32_32x32x16_bf16(vf1, pf, o1, 0, 0, 0);
        }

        __syncthreads();    // DMA drained + all waves done with buf[cur]
        cur ^= 1;
    }

    const float inv = 1.f / lsum;
    const int b = bh >> 4, h = bh & 15;
    const int tq = q0 + q32;
    unsigned* aou = (unsigned*)(ao + ((size_t)(b * T_ + tq)) * D_ + h * HD_);
    #pragma unroll
    for (int pr = 0; pr < 8; ++pr) {
        int d0 = 2 * (pr & 1) + 8 * (pr >> 1) + 4 * hi2;    // even
        aou[d0 >> 1]        = cvtpk(o0[2 * pr] * inv, o0[2 * pr + 1] * inv);
        aou[(32 + d0) >> 1] = cvtpk(o1[2 * pr] * inv, o1[2 * pr + 1] * inv);
    }
}

// ---------------------------------------------------------------------------
extern "C" void kernel_launch(void* const* d_in, const int* in_sizes, int n_in,
                              void* d_out, int out_size, void* d_ws, size_t ws_size,
                              hipStream_t stream) {
    const float* x    = (const float*)d_in[0];
    const float* Wqkv = (const float*)d_in[1];
    const float* bqkv = (const float*)d_in[2];
    const float* Wout = (const float*)d_in[3];
    const float* bout = (const float*)d_in[4];
    float* out = (float*)d_out;

    char* ws = (char*)d_ws;
    short* xb  = (short*)(ws);                      // 8 MB  x bf16 [4096][1024]
    short* WqT = (short*)(ws + ((size_t)8  << 20)); // 6 MB  Wqkv^T bf16 [3072][1024]
    short* WoT = (short*)(ws + ((size_t)14 << 20)); // 2 MB  Wout^T bf16 [1024][1024]
    short* qb  = (short*)(ws + ((size_t)16 << 20)); // 8 MB  q [B*H][T][Hd]
    short* kb  = (short*)(ws + ((size_t)24 << 20)); // 8 MB  k [B*H][T][Hd]
    short* vtb = (short*)(ws + ((size_t)32 << 20)); // 8 MB  v^T [B*H][Hd][T]
    short* aob = (short*)(ws + ((size_t)40 << 20)); // 8 MB  attn out bf16 [4096][1024]

    convert_x<<<(M_TOT * D_ / 8 + 255) / 256, 256, 0, stream>>>(x, xb, M_TOT * D_ / 8);
    transpose_convert2<<<dim3(N_QKV / 64, D_ / 64, 2), 256, 0, stream>>>(
        Wqkv, WqT, Wout, WoT);

    // R27: x = m-tile (32), y = n-tile (24) -> XCD = m%8 colocates A-panels
    gemm_dl<128, 128, 0, 1><<<dim3(M_TOT / 128, N_QKV / 128), 256, 0, stream>>>(
        xb, WqT, bqkv, M_TOT, N_QKV, D_, qb, kb, vtb, nullptr);

    attn<<<dim3(B_ * H_, T_ / 256), 512, 0, stream>>>(qb, kb, vtb, aob);

    // R26: x = m-tile (32), y = n-tile (16) -> XCD = m%8 colocates A-panels
    gemm_dl<128, 64, 1, 1><<<dim3(M_TOT / 128, D_ / 64), 256, 0, stream>>>(
        aob, WoT, bout, M_TOT, D_, D_, nullptr, nullptr, nullptr, out);
}

// Round 28
// 118.815 us; speedup vs baseline: 1.1845x; 1.0153x over previous
//
#include <hip/hip_runtime.h>
#include <hip/hip_bf16.h>

#define B_   2
#define T_   2048
#define D_   1024
#define H_   16
#define HD_  64
#define M_TOT (B_*T_)    // 4096
#define N_QKV (3*D_)     // 3072

typedef __attribute__((ext_vector_type(8))) short bf16x8;
typedef __attribute__((ext_vector_type(4))) float f32x4;
typedef __attribute__((ext_vector_type(16))) float f32x16;

static __device__ __forceinline__ short f2bf(float f) {
    union { __hip_bfloat16 h; short s; } u;
    u.h = __float2bfloat16(f);
    return u.s;
}
static __device__ __forceinline__ unsigned pack2(float a, float b) {
    return (unsigned)(unsigned short)f2bf(a) | ((unsigned)(unsigned short)f2bf(b) << 16);
}
// HW packed f32->bf16 (RNE): D.lo16 = bf16(lo), D.hi16 = bf16(hi). 1 VALU op.
static __device__ __forceinline__ unsigned cvtpk(float lo, float hi) {
    unsigned r;
    asm("v_cvt_pk_bf16_f32 %0, %1, %2" : "=v"(r) : "v"(lo), "v"(hi));
    return r;
}
static __device__ __forceinline__ float exp2_fast(float x) {
    return __builtin_amdgcn_exp2f(x);
}
static __device__ __forceinline__ f32x16 zero16() {
    f32x16 z;
    #pragma unroll
    for (int i = 0; i < 16; ++i) z[i] = 0.f;
    return z;
}
// async global->LDS DMA, 16B per lane. LDS dest = wave-uniform base + lane*16.
static __device__ __forceinline__ void gload16(const void* g, void* l) {
    __builtin_amdgcn_global_load_lds(
        (__attribute__((address_space(1))) unsigned int*)(unsigned long long)g,
        (__attribute__((address_space(3))) unsigned int*)l, 16, 0, 0);
}
// Session ledger: (R9-R12) permlane32_swap failed 2x2 factorial -> shfl_xor
// PV (verified). (R14) counted-vmcnt in attn neutral. (R16) T15 regressed.
// (R17) depth-2 GEMM prefetch neutral (kept). (R18/R19) KV split-K net
// negative. (R20) bh-major attn grid: FETCH 69.7->12.3MB (kept). (R21)
// cvt_pk P-pack -3us (kept). (R22) setprio regressed. (R23) KVBLK=128
// neutral. (R24) 4-wave dedup regressed. (R25) fused weight-transpose
// (kept). (R26) out-proj A-panel colocation -2us (kept). (R27) QKV A-panel
// colocation -0.7us (kept, total 120.6). R28: fuse convert_x into the prep
// kernel as a 3rd z-plane (one fewer dispatch + no tail gap).

// ---------------------------------------------------------------------------
// Fused prep kernel, grid (48, 16, 3):
// z==0: Wqkv[1024][3072] -> WqT[3072][1024] (64x64 LDS transpose tiles)
// z==1: Wout[1024][1024] -> WoT[1024][1024] (bx<16 only; block-uniform ret)
// z==2: x fp32 -> bf16 straight copy, grid-stride over 8-elem chunks
//       (never touches LDS, returns before any barrier -- block-uniform)
__global__ __launch_bounds__(256)
void prep(const float* __restrict__ in0, short* __restrict__ out0,
          const float* __restrict__ in1, short* __restrict__ out1,
          const float* __restrict__ x, short* __restrict__ xb) {
    const int t = threadIdx.x;
    if (blockIdx.z == 2) {
        const int n8 = M_TOT * D_ / 8;                      // 524288 chunks
        const int stride = 48 * 16 * 256;                   // 196608 threads
        for (int i = (blockIdx.y * 48 + blockIdx.x) * 256 + t; i < n8; i += stride) {
            const float4* p = (const float4*)x + (size_t)i * 2;
            float4 a = p[0], b = p[1];
            bf16x8 o;
            o[0]=f2bf(a.x); o[1]=f2bf(a.y); o[2]=f2bf(a.z); o[3]=f2bf(a.w);
            o[4]=f2bf(b.x); o[5]=f2bf(b.y); o[6]=f2bf(b.z); o[7]=f2bf(b.w);
            *((bf16x8*)xb + i) = o;
        }
        return;
    }
    const float* in; short* out; int N;
    if (blockIdx.z == 0) { in = in0; out = out0; N = N_QKV; }
    else {
        if (blockIdx.x >= 16) return;
        in = in1; out = out1; N = D_;
    }
    __shared__ short tile[64][65];
    int k0 = blockIdx.y * 64, n0 = blockIdx.x * 64;
    #pragma unroll
    for (int i = 0; i < 16; ++i) {
        int idx = i * 256 + t;
        int r = idx >> 6, c = idx & 63;
        tile[r][c] = f2bf(in[(size_t)(k0 + r) * N + n0 + c]);
    }
    __syncthreads();
    #pragma unroll
    for (int i = 0; i < 16; ++i) {
        int idx = i * 256 + t;
        int r = idx >> 6, c = idx & 63;     // r: n-local, c: k-local
        out[(size_t)(n0 + r) * D_ + k0 + c] = tile[c][r];
    }
}

// ---------------------------------------------------------------------------
// BK=32 GEMM with depth-2 prefetch (R17-verified). C = A*BT^T + bias.
// SWAP==1: grid axes swapped (x=m-tile, y=n-tile) so XCD=m%8 colocates
// blocks sharing one A-panel (R26/R27; requires gridX % 8 == 0).
#define QSC 0.18033688f   // 0.125 * log2(e)
template<int BM, int BN, int MODE, int SWAP>
__global__ __launch_bounds__(256)
void gemm_dl(const short* __restrict__ A, const short* __restrict__ BT,
             const float* __restrict__ bias, int M, int N, int K,
             short* __restrict__ qo, short* __restrict__ ko,
             short* __restrict__ vo, float* __restrict__ fo) {
    constexpr int BUF = (BM + BN) * 64;        // bytes per stage buffer (64B rows)
    constexpr int NL = (BM + BN) / 64;         // DMA instrs per thread per stage
    __shared__ char smem[3 * BUF];
    const int t = threadIdx.x, w = t >> 6, l = t & 63;
    const int qi_l = l & 15, hi_l = l >> 4;
    const int m0 = (SWAP ? blockIdx.x : blockIdx.y) * BM;
    const int n0 = (SWAP ? blockIdx.y : blockIdx.x) * BN;
    const int wr = w >> 1, wc = w & 1;
    constexpr int MI = BM / 32, NI = BN / 32;

    f32x4 acc[MI][NI];
    #pragma unroll
    for (int mi = 0; mi < MI; ++mi)
        #pragma unroll
        for (int ni = 0; ni < NI; ++ni)
            acc[mi][ni] = (f32x4){0.f, 0.f, 0.f, 0.f};

    const int lrow = l >> 2;                     // 0..15 rows within one 1KB DMA
    const int lch  = ((l & 3) ^ (lrow & 3)) * 8; // pre-swizzled source chunk (elems)

    auto stage = [&](char* dst, int k0) {
        #pragma unroll
        for (int i = 0; i < BM / 64; ++i) {
            int rb = w * (BM / 4) + i * 16;
            gload16(A + (size_t)(m0 + rb + lrow) * K + k0 + lch, dst + rb * 64);
        }
        #pragma unroll
        for (int i = 0; i < BN / 64; ++i) {
            int rb = w * (BN / 4) + i * 16;
            gload16(BT + (size_t)(n0 + rb + lrow) * K + k0 + lch, dst + BM * 64 + rb * 64);
        }
    };

    const int nt = K / 32;
    stage(smem, 0);
    if (nt > 1) stage(smem + BUF, 32);
    for (int it = 0; it < nt; ++it) {
        if (it + 2 < nt) {
            stage(smem + ((it + 2) % 3) * BUF, (it + 2) * 32);  // t+2 in flight
            if constexpr (NL == 4)      asm volatile("s_waitcnt vmcnt(8)" ::: "memory");
            else if constexpr (NL == 3) asm volatile("s_waitcnt vmcnt(6)" ::: "memory");
            else                        asm volatile("s_waitcnt vmcnt(0)" ::: "memory");
        } else if (it + 1 < nt) {
            if constexpr (NL == 4)      asm volatile("s_waitcnt vmcnt(4)" ::: "memory");
            else if constexpr (NL == 3) asm volatile("s_waitcnt vmcnt(3)" ::: "memory");
            else                        asm volatile("s_waitcnt vmcnt(0)" ::: "memory");
        } else {
            asm volatile("s_waitcnt vmcnt(0)" ::: "memory");
        }
        __builtin_amdgcn_s_barrier();    // B1: tile t visible to all waves

        char* sA = smem + (it % 3) * BUF;
        char* sB = sA + BM * 64;
        bf16x8 af[MI], bfr[NI];
        #pragma unroll
        for (int mi = 0; mi < MI; ++mi) {
            int row = wr * (BM / 2) + mi * 16 + qi_l;
            int ad = row * 64 + ((hi_l ^ (row & 3)) * 16);
            af[mi] = *(const bf16x8*)(sA + ad);
        }
        #pragma unroll
        for (int ni = 0; ni < NI; ++ni) {
            int row = wc * (BN / 2) + ni * 16 + qi_l;
            int ad = row * 64 + ((hi_l ^ (row & 3)) * 16);
            bfr[ni] = *(const bf16x8*)(sB + ad);
        }
        #pragma unroll
        for (int mi = 0; mi < MI; ++mi)
            #pragma unroll
            for (int ni = 0; ni < NI; ++ni)
                acc[mi][ni] = __builtin_amdgcn_mfma_f32_16x16x32_bf16(af[mi], bfr[ni], acc[mi][ni], 0, 0, 0);

        __builtin_amdgcn_s_barrier();    // B2: buf[it%3] reads done
    }

    #pragma unroll
    for (int mi = 0; mi < MI; ++mi) {
        int rbase = m0 + wr * (BM / 2) + mi * 16 + 4 * hi_l;
        #pragma unroll
        for (int ni = 0; ni < NI; ++ni) {
            int n = n0 + wc * (BN / 2) + ni * 16 + qi_l;
            float bv = bias[n];
            #pragma unroll
            for (int r = 0; r < 4; ++r) {
                int mm = rbase + r;
                float c = acc[mi][ni][r] + bv;
                if (MODE == 0) {
                    int which = n >> 10, rest = n & 1023;
                    int h = rest >> 6, d = rest & 63;
                    int b = mm >> 11, tq = mm & 2047;
                    size_t bh = (size_t)(b * H_ + h);
                    if (which == 0)      qo[(bh * T_ + tq) * HD_ + d] = f2bf(c * QSC);
                    else if (which == 1) ko[(bh * T_ + tq) * HD_ + d] = f2bf(c);
                    else                 vo[(bh * HD_ + d) * T_ + tq] = f2bf(c);
                } else {
                    fo[(size_t)mm * N + n] = c;
                }
            }
        }
    }
}

// ---------------------------------------------------------------------------
// Flash attention (best verified: R21 body): bh-major grid (XCD=bh%8 L2
// locality), 8 waves x 32 q-rows (QBLK=256), KVBLK=64, swapped 32x32 MFMA,
// HW cvt_pk P-pack, shfl_xor PV redistribution, cvtpk epilogue.
// q,k: [B*H, T, Hd] bf16 (q pre-scaled by 1/8*log2e); vt: [B*H, Hd, T] bf16.
__global__ __launch_bounds__(512)
void attn(const short* __restrict__ q, const short* __restrict__ k,
          const short* __restrict__ vt, short* __restrict__ ao) {
    __shared__ char smem[32768];   // buf0: K@0 V@8192; buf1: K@16384 V@24576

    const int t = threadIdx.x, w = t >> 6, l = t & 63;
    const int q32 = l & 31, hi2 = l >> 5;
    const int swz = (l & 7) << 4;
    const int bh = blockIdx.x;                     // bh on x: XCD = bh % 8
    const int q0 = blockIdx.y * 256 + w * 32;      // q-tile on y

    const short* qptr = q + ((size_t)bh * T_ + q0) * HD_;
    const short* kbase = k + (size_t)bh * T_ * HD_;
    const short* vbase = vt + (size_t)bh * HD_ * T_;

    const int srow = w * 8 + (l >> 3);              // staging row (this wave: 8 rows)
    const int sch  = ((l & 7) ^ (l >> 3)) * 8;      // pre-swizzled source chunk

    // Q fragments: B-operand of 32x32x16: lane holds Q[q=q32][d = kc*16 + hi2*8 + j]
    bf16x8 qa[4];
    #pragma unroll
    for (int kc = 0; kc < 4; ++kc)
        qa[kc] = *(const bf16x8*)(qptr + q32 * HD_ + kc * 16 + hi2 * 8);

    f32x16 o0 = zero16(), o1 = zero16();
    float m = -1e30f, lsum = 0.f;

    // prologue: stage tile 0 into buf 0 (1 K + 1 V DMA per thread)
    gload16(kbase + (size_t)srow * HD_ + sch, smem + srow * 128);
    gload16(vbase + (size_t)srow * T_ + sch,  smem + 8192 + srow * 128);
    __syncthreads();

    int cur = 0;
    for (int kb = 0; kb < T_; kb += 64) {
        char* sK = smem + cur * 16384;
        char* sV = sK + 8192;
        if (kb + 64 < T_) {
            char* nK = smem + (cur ^ 1) * 16384;
            gload16(kbase + (size_t)(kb + 64 + srow) * HD_ + sch, nK + srow * 128);
            gload16(vbase + (size_t)srow * T_ + (kb + 64) + sch,  nK + 8192 + srow * 128);
        }

        // S^T: two 32x32 tiles (kvt=0,1), accumulate over Hd in 4 chunks of 16
        f32x16 s0 = zero16(), s1 = zero16();
        #pragma unroll
        for (int kc = 0; kc < 4; ++kc) {
            int off = (kc * 32 + hi2 * 16) ^ swz;
            bf16x8 kf0 = *(const bf16x8*)(sK + q32 * 128 + off);
            s0 = __builtin_amdgcn_mfma_f32_32x32x16_bf16(kf0, qa[kc], s0, 0, 0, 0);
            bf16x8 kf1 = *(const bf16x8*)(sK + (32 + q32) * 128 + off);
            s1 = __builtin_amdgcn_mfma_f32_32x32x16_bf16(kf1, qa[kc], s1, 0, 0, 0);
        }

        // row max: 32 in-lane (tree) + 1 exchange with lane^32
        float a8[8];
        #pragma unroll
        for (int i = 0; i < 8; ++i)
            a8[i] = fmaxf(fmaxf(s0[i], s0[i + 8]), fmaxf(s1[i], s1[i + 8]));
        float b4_0 = fmaxf(a8[0], a8[1]), b4_1 = fmaxf(a8[2], a8[3]);
        float b4_2 = fmaxf(a8[4], a8[5]), b4_3 = fmaxf(a8[6], a8[7]);
        float tm = fmaxf(fmaxf(b4_0, b4_1), fmaxf(b4_2, b4_3));
        tm = fmaxf(tm, __shfl_xor(tm, 32));

        // defer-max (T13): skip O-rescale when max growth <= 8 (log2 domain)
        if (!__all(tm <= m + 8.f)) {
            float mnew = fmaxf(m, tm);
            float fsc = exp2_fast(m - mnew);
            lsum *= fsc;
            #pragma unroll
            for (int i = 0; i < 16; ++i) { o0[i] *= fsc; o1[i] *= fsc; }
            m = mnew;
        }

        // P = exp2(S - m); row-sum (tree + 1 shfl); pack to bf16 pairs (HW cvt_pk)
        #pragma unroll
        for (int i = 0; i < 16; ++i) {
            s0[i] = exp2_fast(s0[i] - m);
            s1[i] = exp2_fast(s1[i] - m);
        }
        float p8[8];
        #pragma unroll
        for (int i = 0; i < 8; ++i)
            p8[i] = (s0[i] + s0[i + 8]) + (s1[i] + s1[i + 8]);
        float psum = ((p8[0] + p8[1]) + (p8[2] + p8[3])) + ((p8[4] + p8[5]) + (p8[6] + p8[7]));
        psum += __shfl_xor(psum, 32);
        lsum += psum;

        unsigned pk0[8], pk1[8];
        #pragma unroll
        for (int p = 0; p < 8; ++p) {
            pk0[p] = cvtpk(s0[2 * p], s0[2 * p + 1]);
            pk1[p] = cvtpk(s1[2 * p], s1[2 * p + 1]);
        }

        // PV: for each 16-kv chunk c, build P^T B-fragment in-register
        // (shfl_xor lane+-32 exchange -- VERIFIED mapping) and accumulate
        // O^T (two 32-row d-tiles) over the kv dimension.
        #pragma unroll
        for (int c = 0; c < 4; ++c) {
            unsigned w0 = (c & 2) ? pk1[(c & 1) * 4 + 0] : pk0[(c & 1) * 4 + 0];
            unsigned w1 = (c & 2) ? pk1[(c & 1) * 4 + 1] : pk0[(c & 1) * 4 + 1];
            unsigned w2 = (c & 2) ? pk1[(c & 1) * 4 + 2] : pk0[(c & 1) * 4 + 2];
            unsigned w3 = (c & 2) ? pk1[(c & 1) * 4 + 3] : pk0[(c & 1) * 4 + 3];
            unsigned t0 = hi2 ? w0 : w2;
            unsigned t1 = hi2 ? w1 : w3;
            unsigned r0 = __shfl_xor(t0, 32);
            unsigned r1 = __shfl_xor(t1, 32);
            union { unsigned u[4]; bf16x8 v; } uf;
            uf.u[0] = hi2 ? r0 : w0;
            uf.u[1] = hi2 ? r1 : w1;
            uf.u[2] = hi2 ? w2 : r0;
            uf.u[3] = hi2 ? w3 : r1;
            bf16x8 pf = uf.v;

            int off = (c * 32 + hi2 * 16) ^ swz;
            bf16x8 vf0 = *(const bf16x8*)(sV + q32 * 128 + off);
            o0 = __builtin_amdgcn_mfma_f32_32x32x16_bf16(vf0, pf, o0, 0, 0, 0);
            bf16x8 vf1 = *(const bf16x8*)(sV + (32 + q32) * 128 + off);
            o1 = __builtin_amdgcn_mfma_f32_32x32x16_bf16(vf1, pf, o1, 0, 0, 0);
        }

        __syncthreads();    // DMA drained + all waves done with buf[cur]
        cur ^= 1;
    }

    const float inv = 1.f / lsum;
    const int b = bh >> 4, h = bh & 15;
    const int tq = q0 + q32;
    unsigned* aou = (unsigned*)(ao + ((size_t)(b * T_ + tq)) * D_ + h * HD_);
    #pragma unroll
    for (int pr = 0; pr < 8; ++pr) {
        int d0 = 2 * (pr & 1) + 8 * (pr >> 1) + 4 * hi2;    // even
        aou[d0 >> 1]        = cvtpk(o0[2 * pr] * inv, o0[2 * pr + 1] * inv);
        aou[(32 + d0) >> 1] = cvtpk(o1[2 * pr] * inv, o1[2 * pr + 1] * inv);
    }
}

// ---------------------------------------------------------------------------
extern "C" void kernel_launch(void* const* d_in, const int* in_sizes, int n_in,
                              void* d_out, int out_size, void* d_ws, size_t ws_size,
                              hipStream_t stream) {
    const float* x    = (const float*)d_in[0];
    const float* Wqkv = (const float*)d_in[1];
    const float* bqkv = (const float*)d_in[2];
    const float* Wout = (const float*)d_in[3];
    const float* bout = (const float*)d_in[4];
    float* out = (float*)d_out;

    char* ws = (char*)d_ws;
    short* xb  = (short*)(ws);                      // 8 MB  x bf16 [4096][1024]
    short* WqT = (short*)(ws + ((size_t)8  << 20)); // 6 MB  Wqkv^T bf16 [3072][1024]
    short* WoT = (short*)(ws + ((size_t)14 << 20)); // 2 MB  Wout^T bf16 [1024][1024]
    short* qb  = (short*)(ws + ((size_t)16 << 20)); // 8 MB  q [B*H][T][Hd]
    short* kb  = (short*)(ws + ((size_t)24 << 20)); // 8 MB  k [B*H][T][Hd]
    short* vtb = (short*)(ws + ((size_t)32 << 20)); // 8 MB  v^T [B*H][Hd][T]
    short* aob = (short*)(ws + ((size_t)40 << 20)); // 8 MB  attn out bf16 [4096][1024]

    // R28: single prep dispatch (x-convert + both weight transposes)
    prep<<<dim3(N_QKV / 64, D_ / 64, 3), 256, 0, stream>>>(
        Wqkv, WqT, Wout, WoT, x, xb);

    // R27: x = m-tile (32), y = n-tile (24) -> XCD = m%8 colocates A-panels
    gemm_dl<128, 128, 0, 1><<<dim3(M_TOT / 128, N_QKV / 128), 256, 0, stream>>>(
        xb, WqT, bqkv, M_TOT, N_QKV, D_, qb, kb, vtb, nullptr);

    attn<<<dim3(B_ * H_, T_ / 256), 512, 0, stream>>>(qb, kb, vtb, aob);

    // R26: x = m-tile (32), y = n-tile (16) -> XCD = m%8 colocates A-panels
    gemm_dl<128, 64, 1, 1><<<dim3(M_TOT / 128, D_ / 64), 256, 0, stream>>>(
        aob, WoT, bout, M_TOT, D_, D_, nullptr, nullptr, nullptr, out);
}